// Round 1
// baseline (2570.704 us; speedup 1.0000x reference)
//
#include <hip/hip_runtime.h>

#define N_FUNC 200000
#define N_API  50000
#define H      64
#define NLAYERS 2

__device__ inline void fma4(float4& a, float s, float4 w) {
    a.x = fmaf(s, w.x, a.x); a.y = fmaf(s, w.y, a.y);
    a.z = fmaf(s, w.z, a.z); a.w = fmaf(s, w.w, a.w);
}

// out[k*64+o] = A[o*K+k] (+ B[o*K+k]) : transpose (64,K)->(K,64), optional add
__global__ __launch_bounds__(256) void transpose_w(const float* __restrict__ A,
        const float* __restrict__ B, float* __restrict__ out, int K)
{
    int idx = blockIdx.x * 256 + threadIdx.x;
    if (idx >= K * 64) return;
    int k = idx / 64, o = idx - k * 64;
    float v = A[o * K + k];
    if (B) v += B[o * K + k];
    out[k * 64 + o] = v;
}

__global__ __launch_bounds__(256) void count_edges(const int* __restrict__ dst,
        float* __restrict__ cnt, int nE)
{
    for (int e = blockIdx.x * 256 + threadIdx.x; e < nE; e += gridDim.x * 256)
        atomicAdd(&cnt[dst[e]], 1.0f);
}

// one edge per 16 lanes; float4 gather + 4 scalar f32 atomics scatter
__global__ __launch_bounds__(256) void agg_edges(const float* __restrict__ hsrc,
        const int* __restrict__ src, const int* __restrict__ dst,
        float* __restrict__ agg, int nE)
{
    int t = blockIdx.x * 256 + threadIdx.x;
    int lane = t & 15;
    int e = t >> 4;
    if (e >= nE) return;
    int s = src[e], d = dst[e];
    float4 v = *reinterpret_cast<const float4*>(hsrc + (size_t)s * H + lane * 4);
    float* base = agg + (size_t)d * H + lane * 4;
    atomicAdd(base + 0, v.x);
    atomicAdd(base + 1, v.y);
    atomicAdd(base + 2, v.z);
    atomicAdd(base + 3, v.w);
}

// h = relu(x @ W.T + b); W pre-transposed to (K,64). 64 nodes/block, 4 nodes+4 outs/thread.
template<int K>
__global__ __launch_bounds__(256) void proj_kernel(const float* __restrict__ x,
        const float* __restrict__ wt, const float* __restrict__ bias,
        float* __restrict__ hout, int nN)
{
    constexpr int KQ = K / 4;
    __shared__ float4 xs[64][KQ];
    const int i0 = blockIdx.x * 64;
    const int t = threadIdx.x;
    for (int idx = t; idx < 64 * KQ; idx += 256) {
        int n = idx / KQ, k4 = idx - n * KQ;
        float4 v = make_float4(0.f, 0.f, 0.f, 0.f);
        if (i0 + n < nN)
            v = *reinterpret_cast<const float4*>(x + (size_t)(i0 + n) * K + k4 * 4);
        xs[n][k4 ^ ((n >> 2) & 7)] = v;   // XOR swizzle: conflict-free b128 reads
    }
    __syncthreads();
    const int og = t & 15, ng = t >> 4;
    float4 acc[4];
    #pragma unroll
    for (int j = 0; j < 4; ++j) acc[j] = make_float4(0.f, 0.f, 0.f, 0.f);
    const float4* w4 = reinterpret_cast<const float4*>(wt);
    for (int k4 = 0; k4 < KQ; ++k4) {
        float4 w0 = w4[(4 * k4 + 0) * 16 + og];
        float4 w1 = w4[(4 * k4 + 1) * 16 + og];
        float4 w2 = w4[(4 * k4 + 2) * 16 + og];
        float4 w3 = w4[(4 * k4 + 3) * 16 + og];
        #pragma unroll
        for (int j = 0; j < 4; ++j) {
            int n = ng * 4 + j;
            float4 xv = xs[n][k4 ^ ((n >> 2) & 7)];
            fma4(acc[j], xv.x, w0); fma4(acc[j], xv.y, w1);
            fma4(acc[j], xv.z, w2); fma4(acc[j], xv.w, w3);
        }
    }
    float4 b = reinterpret_cast<const float4*>(bias)[og];
    #pragma unroll
    for (int j = 0; j < 4; ++j) {
        int node = i0 + ng * 4 + j;
        if (node < nN) {
            float4 o;
            o.x = fmaxf(acc[j].x + b.x, 0.f);
            o.y = fmaxf(acc[j].y + b.y, 0.f);
            o.z = fmaxf(acc[j].z + b.z, 0.f);
            o.w = fmaxf(acc[j].w + b.w, 0.f);
            *reinterpret_cast<float4*>(hout + (size_t)node * H + og * 4) = o;
        }
    }
}

// in-place: h = relu(mean_c @ Wlc.T + mean_u @ Wlu.T + h @ (Wrc+Wru).T + b1 + b2)
__global__ __launch_bounds__(256) void layer_func_kernel(float* __restrict__ h,
        const float* __restrict__ aggc, const float* __restrict__ cntc,
        const float* __restrict__ aggu, const float* __restrict__ cntu,
        const float* __restrict__ wtr, const float* __restrict__ wtlc,
        const float* __restrict__ wtlu, const float* __restrict__ b1,
        const float* __restrict__ b2, int nN)
{
    __shared__ float4 hs[64][16], as_[64][16], us[64][16];
    const int i0 = blockIdx.x * 64;
    const int t = threadIdx.x;
    for (int idx = t; idx < 1024; idx += 256) {
        int n = idx >> 4, k4 = idx & 15;
        int node = i0 + n;
        float4 hv = make_float4(0.f, 0.f, 0.f, 0.f), av = hv, uv = hv;
        if (node < nN) {
            float rc = 1.0f / fmaxf(cntc[node], 1.0f);
            float ru = 1.0f / fmaxf(cntu[node], 1.0f);
            hv = *reinterpret_cast<const float4*>(h    + (size_t)node * H + k4 * 4);
            av = *reinterpret_cast<const float4*>(aggc + (size_t)node * H + k4 * 4);
            uv = *reinterpret_cast<const float4*>(aggu + (size_t)node * H + k4 * 4);
            av.x *= rc; av.y *= rc; av.z *= rc; av.w *= rc;
            uv.x *= ru; uv.y *= ru; uv.z *= ru; uv.w *= ru;
        }
        int sw = k4 ^ ((n >> 2) & 7);
        hs[n][sw] = hv; as_[n][sw] = av; us[n][sw] = uv;
    }
    __syncthreads();
    const int og = t & 15, ng = t >> 4;
    float4 acc[4];
    #pragma unroll
    for (int j = 0; j < 4; ++j) acc[j] = make_float4(0.f, 0.f, 0.f, 0.f);
    const float4* wr4 = reinterpret_cast<const float4*>(wtr);
    const float4* wc4 = reinterpret_cast<const float4*>(wtlc);
    const float4* wu4 = reinterpret_cast<const float4*>(wtlu);
    for (int k4 = 0; k4 < 16; ++k4) {
        float4 r0 = wr4[(4 * k4 + 0) * 16 + og], r1 = wr4[(4 * k4 + 1) * 16 + og];
        float4 r2 = wr4[(4 * k4 + 2) * 16 + og], r3 = wr4[(4 * k4 + 3) * 16 + og];
        float4 c0 = wc4[(4 * k4 + 0) * 16 + og], c1 = wc4[(4 * k4 + 1) * 16 + og];
        float4 c2 = wc4[(4 * k4 + 2) * 16 + og], c3 = wc4[(4 * k4 + 3) * 16 + og];
        float4 u0 = wu4[(4 * k4 + 0) * 16 + og], u1 = wu4[(4 * k4 + 1) * 16 + og];
        float4 u2 = wu4[(4 * k4 + 2) * 16 + og], u3 = wu4[(4 * k4 + 3) * 16 + og];
        #pragma unroll
        for (int j = 0; j < 4; ++j) {
            int n = ng * 4 + j;
            int sw = k4 ^ ((n >> 2) & 7);
            float4 xh = hs[n][sw], xa = as_[n][sw], xu = us[n][sw];
            fma4(acc[j], xh.x, r0); fma4(acc[j], xh.y, r1);
            fma4(acc[j], xh.z, r2); fma4(acc[j], xh.w, r3);
            fma4(acc[j], xa.x, c0); fma4(acc[j], xa.y, c1);
            fma4(acc[j], xa.z, c2); fma4(acc[j], xa.w, c3);
            fma4(acc[j], xu.x, u0); fma4(acc[j], xu.y, u1);
            fma4(acc[j], xu.z, u2); fma4(acc[j], xu.w, u3);
        }
    }
    float4 ba = reinterpret_cast<const float4*>(b1)[og];
    float4 bb = reinterpret_cast<const float4*>(b2)[og];
    float4 b = make_float4(ba.x + bb.x, ba.y + bb.y, ba.z + bb.z, ba.w + bb.w);
    #pragma unroll
    for (int j = 0; j < 4; ++j) {
        int node = i0 + ng * 4 + j;
        if (node < nN) {
            float4 o;
            o.x = fmaxf(acc[j].x + b.x, 0.f);
            o.y = fmaxf(acc[j].y + b.y, 0.f);
            o.z = fmaxf(acc[j].z + b.z, 0.f);
            o.w = fmaxf(acc[j].w + b.w, 0.f);
            *reinterpret_cast<float4*>(h + (size_t)node * H + og * 4) = o;
        }
    }
}

// in-place: h_api = relu(mean_a @ Wl.T + h_api @ Wr.T + b)
__global__ __launch_bounds__(256) void layer_api_kernel(float* __restrict__ h,
        const float* __restrict__ agga, const float* __restrict__ cnta,
        const float* __restrict__ wtr, const float* __restrict__ wtl,
        const float* __restrict__ b1, int nN)
{
    __shared__ float4 hs[64][16], as_[64][16];
    const int i0 = blockIdx.x * 64;
    const int t = threadIdx.x;
    for (int idx = t; idx < 1024; idx += 256) {
        int n = idx >> 4, k4 = idx & 15;
        int node = i0 + n;
        float4 hv = make_float4(0.f, 0.f, 0.f, 0.f), av = hv;
        if (node < nN) {
            float ra = 1.0f / fmaxf(cnta[node], 1.0f);
            hv = *reinterpret_cast<const float4*>(h    + (size_t)node * H + k4 * 4);
            av = *reinterpret_cast<const float4*>(agga + (size_t)node * H + k4 * 4);
            av.x *= ra; av.y *= ra; av.z *= ra; av.w *= ra;
        }
        int sw = k4 ^ ((n >> 2) & 7);
        hs[n][sw] = hv; as_[n][sw] = av;
    }
    __syncthreads();
    const int og = t & 15, ng = t >> 4;
    float4 acc[4];
    #pragma unroll
    for (int j = 0; j < 4; ++j) acc[j] = make_float4(0.f, 0.f, 0.f, 0.f);
    const float4* wr4 = reinterpret_cast<const float4*>(wtr);
    const float4* wl4 = reinterpret_cast<const float4*>(wtl);
    for (int k4 = 0; k4 < 16; ++k4) {
        float4 r0 = wr4[(4 * k4 + 0) * 16 + og], r1 = wr4[(4 * k4 + 1) * 16 + og];
        float4 r2 = wr4[(4 * k4 + 2) * 16 + og], r3 = wr4[(4 * k4 + 3) * 16 + og];
        float4 c0 = wl4[(4 * k4 + 0) * 16 + og], c1 = wl4[(4 * k4 + 1) * 16 + og];
        float4 c2 = wl4[(4 * k4 + 2) * 16 + og], c3 = wl4[(4 * k4 + 3) * 16 + og];
        #pragma unroll
        for (int j = 0; j < 4; ++j) {
            int n = ng * 4 + j;
            int sw = k4 ^ ((n >> 2) & 7);
            float4 xh = hs[n][sw], xa = as_[n][sw];
            fma4(acc[j], xh.x, r0); fma4(acc[j], xh.y, r1);
            fma4(acc[j], xh.z, r2); fma4(acc[j], xh.w, r3);
            fma4(acc[j], xa.x, c0); fma4(acc[j], xa.y, c1);
            fma4(acc[j], xa.z, c2); fma4(acc[j], xa.w, c3);
        }
    }
    float4 b = reinterpret_cast<const float4*>(b1)[og];
    #pragma unroll
    for (int j = 0; j < 4; ++j) {
        int node = i0 + ng * 4 + j;
        if (node < nN) {
            float4 o;
            o.x = fmaxf(acc[j].x + b.x, 0.f);
            o.y = fmaxf(acc[j].y + b.y, 0.f);
            o.z = fmaxf(acc[j].z + b.z, 0.f);
            o.w = fmaxf(acc[j].w + b.w, 0.f);
            *reinterpret_cast<float4*>(h + (size_t)node * H + og * 4) = o;
        }
    }
}

__global__ __launch_bounds__(256) void pool_sum(const float* __restrict__ h,
        float* __restrict__ out, int nN)
{
    __shared__ float red[4][64];
    int c = threadIdx.x & 63, rl = threadIdx.x >> 6;
    float s = 0.f;
    for (int r = blockIdx.x * 4 + rl; r < nN; r += gridDim.x * 4)
        s += h[(size_t)r * H + c];
    red[rl][c] = s;
    __syncthreads();
    if (threadIdx.x < 64) {
        float v = red[0][c] + red[1][c] + red[2][c] + red[3][c];
        atomicAdd(&out[c], v);
    }
}

__global__ __launch_bounds__(128) void classifier_kernel(const float* __restrict__ pooled,
        const float* __restrict__ Wc1, const float* __restrict__ bc1,
        const float* __restrict__ Wc2, const float* __restrict__ bc2,
        float* __restrict__ out)
{
    __shared__ float ps[128];
    __shared__ float z1[64];
    int t = threadIdx.x;
    ps[t] = pooled[t] * (t < 64 ? (1.0f / N_FUNC) : (1.0f / N_API));
    __syncthreads();
    if (t < 64) {
        float a = bc1[t];
        for (int k = 0; k < 128; ++k) a = fmaf(ps[k], Wc1[t * 128 + k], a);
        z1[t] = fmaxf(a, 0.f);
    }
    __syncthreads();
    if (t < 2) {
        float a = bc2[t];
        for (int j = 0; j < 64; ++j) a = fmaf(z1[j], Wc2[t * 64 + j], a);
        out[t] = a;
    }
}

extern "C" void kernel_launch(void* const* d_in, const int* in_sizes, int n_in,
                              void* d_out, int out_size, void* d_ws, size_t ws_size,
                              hipStream_t stream)
{
    const float* x_func    = (const float*)d_in[0];
    const float* x_api     = (const float*)d_in[1];
    const float* w_in_func = (const float*)d_in[2];
    const float* b_in_func = (const float*)d_in[3];
    const float* w_in_api  = (const float*)d_in[4];
    const float* b_in_api  = (const float*)d_in[5];
    const float* Wl_calls  = (const float*)d_in[6];
    const float* bl_calls  = (const float*)d_in[7];
    const float* Wr_calls  = (const float*)d_in[8];
    const float* Wl_uses   = (const float*)d_in[9];
    const float* bl_uses   = (const float*)d_in[10];
    const float* Wr_uses   = (const float*)d_in[11];
    const float* Wl_usedby = (const float*)d_in[12];
    const float* bl_usedby = (const float*)d_in[13];
    const float* Wr_usedby = (const float*)d_in[14];
    const float* Wc1       = (const float*)d_in[15];
    const float* bc1       = (const float*)d_in[16];
    const float* Wc2       = (const float*)d_in[17];
    const float* bc2       = (const float*)d_in[18];
    const int*   ei_calls  = (const int*)d_in[19];
    const int*   ei_uses   = (const int*)d_in[20];
    const int*   ei_usedby = (const int*)d_in[21];
    const int E = in_sizes[19] / 2;

    float* ws = (float*)d_ws;
    size_t off = 0;
    float* h_func = ws + off; off += (size_t)N_FUNC * H;
    float* h_api  = ws + off; off += (size_t)N_API * H;
    float* agg_c  = ws + off; off += (size_t)N_FUNC * H;   // agg_c/agg_u/agg_a contiguous
    float* agg_u  = ws + off; off += (size_t)N_FUNC * H;
    float* agg_a  = ws + off; off += (size_t)N_API * H;
    float* cnt_c  = ws + off; off += N_FUNC;               // cnt_* and pooled contiguous
    float* cnt_u  = ws + off; off += N_FUNC;
    float* cnt_a  = ws + off; off += N_API;
    float* pooled = ws + off; off += 128;
    float* wt_in_func = ws + off; off += 128 * 64;
    float* wt_in_api  = ws + off; off += 64 * 64;
    float* wt_r[NLAYERS], *wt_lc[NLAYERS], *wt_lu[NLAYERS], *wt_luse[NLAYERS], *wt_ruse[NLAYERS];
    for (int l = 0; l < NLAYERS; ++l) {
        wt_r[l]    = ws + off; off += 4096;
        wt_lc[l]   = ws + off; off += 4096;
        wt_lu[l]   = ws + off; off += 4096;
        wt_luse[l] = ws + off; off += 4096;
        wt_ruse[l] = ws + off; off += 4096;
    }

    // zero counts + pooled (contiguous region), once per call
    hipMemsetAsync(cnt_c, 0, (size_t)(2 * N_FUNC + N_API + 128) * sizeof(float), stream);

    // transposed (+combined) weights
    transpose_w<<<32, 256, 0, stream>>>(w_in_func, nullptr, wt_in_func, 128);
    transpose_w<<<16, 256, 0, stream>>>(w_in_api, nullptr, wt_in_api, 64);
    for (int l = 0; l < NLAYERS; ++l) {
        transpose_w<<<16, 256, 0, stream>>>(Wr_calls + l * 4096, Wr_usedby + l * 4096, wt_r[l], 64);
        transpose_w<<<16, 256, 0, stream>>>(Wl_calls + l * 4096, nullptr, wt_lc[l], 64);
        transpose_w<<<16, 256, 0, stream>>>(Wl_usedby + l * 4096, nullptr, wt_lu[l], 64);
        transpose_w<<<16, 256, 0, stream>>>(Wl_uses + l * 4096, nullptr, wt_luse[l], 64);
        transpose_w<<<16, 256, 0, stream>>>(Wr_uses + l * 4096, nullptr, wt_ruse[l], 64);
    }

    // degree counts (layer-invariant)
    count_edges<<<1024, 256, 0, stream>>>(ei_calls + E, cnt_c, E);
    count_edges<<<1024, 256, 0, stream>>>(ei_usedby + E, cnt_u, E);
    count_edges<<<1024, 256, 0, stream>>>(ei_uses + E, cnt_a, E);

    // input projections
    proj_kernel<128><<<(N_FUNC + 63) / 64, 256, 0, stream>>>(x_func, wt_in_func, b_in_func, h_func, N_FUNC);
    proj_kernel<64><<<(N_API + 63) / 64, 256, 0, stream>>>(x_api, wt_in_api, b_in_api, h_api, N_API);

    const int aggBlocks = (E * 16 + 255) / 256;
    for (int l = 0; l < NLAYERS; ++l) {
        hipMemsetAsync(agg_c, 0, (size_t)(2 * N_FUNC + N_API) * H * sizeof(float), stream);
        agg_edges<<<aggBlocks, 256, 0, stream>>>(h_func, ei_calls, ei_calls + E, agg_c, E);
        agg_edges<<<aggBlocks, 256, 0, stream>>>(h_api, ei_usedby, ei_usedby + E, agg_u, E);
        agg_edges<<<aggBlocks, 256, 0, stream>>>(h_func, ei_uses, ei_uses + E, agg_a, E);
        layer_func_kernel<<<(N_FUNC + 63) / 64, 256, 0, stream>>>(h_func, agg_c, cnt_c, agg_u, cnt_u,
                wt_r[l], wt_lc[l], wt_lu[l], bl_calls + l * 64, bl_usedby + l * 64, N_FUNC);
        layer_api_kernel<<<(N_API + 63) / 64, 256, 0, stream>>>(h_api, agg_a, cnt_a,
                wt_ruse[l], wt_luse[l], bl_uses + l * 64, N_API);
    }

    pool_sum<<<512, 256, 0, stream>>>(h_func, pooled, N_FUNC);
    pool_sum<<<512, 256, 0, stream>>>(h_api, pooled + 64, N_API);
    classifier_kernel<<<1, 128, 0, stream>>>(pooled, Wc1, bc1, Wc2, bc2, (float*)d_out);
}

// Round 2
// 710.871 us; speedup vs baseline: 3.6163x; 3.6163x over previous
//
#include <hip/hip_runtime.h>

#define N_FUNC 200000
#define N_API  50000
#define H      64
#define NLAYERS 2
#define SCAN_CHUNK 2048

__device__ inline void fma4(float4& a, float s, float4 w) {
    a.x = fmaf(s, w.x, a.x); a.y = fmaf(s, w.y, a.y);
    a.z = fmaf(s, w.z, a.z); a.w = fmaf(s, w.w, a.w);
}
__device__ inline void add4(float4& a, float4 v) {
    a.x += v.x; a.y += v.y; a.z += v.z; a.w += v.w;
}
__device__ inline void scl4(float4& a, float s) {
    a.x *= s; a.y *= s; a.z *= s; a.w *= s;
}

// ---- weight prep: all transposes (+Wr combine) in ONE launch ----
// layout: [0,8192) wt_in_func (128x64); [8192,12288) wt_in_api (64x64);
// then per layer l, 5 matrices of 4096: wt_r(=Wrc+Wru), wt_lc, wt_lu, wt_luse, wt_ruse
__global__ __launch_bounds__(256) void prep_weights(
        const float* __restrict__ w_in_func, const float* __restrict__ w_in_api,
        const float* __restrict__ Wl_calls, const float* __restrict__ Wr_calls,
        const float* __restrict__ Wl_uses,  const float* __restrict__ Wr_uses,
        const float* __restrict__ Wl_usedby,const float* __restrict__ Wr_usedby,
        float* __restrict__ out)
{
    int idx = blockIdx.x * 256 + threadIdx.x;
    if (idx < 8192) {
        int k = idx >> 6, o = idx & 63;
        out[idx] = w_in_func[o * 128 + k];
    } else if (idx < 12288) {
        int r = idx - 8192; int k = r >> 6, o = r & 63;
        out[idx] = w_in_api[o * 64 + k];
    } else if (idx < 12288 + 10 * 4096) {
        int r = idx - 12288;
        int m = r >> 12, w = r & 4095;
        int k = w >> 6, o = w & 63;
        int l = m / 5, which = m - 5 * l;
        const float* A; const float* B = nullptr;
        if (which == 0)      { A = Wr_calls  + l * 4096; B = Wr_usedby + l * 4096; }
        else if (which == 1)   A = Wl_calls  + l * 4096;
        else if (which == 2)   A = Wl_usedby + l * 4096;
        else if (which == 3)   A = Wl_uses   + l * 4096;
        else                   A = Wr_uses   + l * 4096;
        float v = A[o * 64 + k];
        if (B) v += B[o * 64 + k];
        out[idx] = v;
    }
}

// ---- CSR build (3 relations batched) ----
__global__ __launch_bounds__(256) void count_all(
        const int* __restrict__ dC, const int* __restrict__ dU, const int* __restrict__ dA,
        int* __restrict__ cC, int* __restrict__ cU, int* __restrict__ cA, int E)
{
    int i = blockIdx.x * 256 + threadIdx.x;
    if (i >= 3 * E) return;
    int rel = i / E, e = i - rel * E;
    if (rel == 0)      atomicAdd(&cC[dC[e]], 1);
    else if (rel == 1) atomicAdd(&cU[dU[e]], 1);
    else               atomicAdd(&cA[dA[e]], 1);
}

__global__ __launch_bounds__(256) void block_sums_all(
        const int* __restrict__ cC, const int* __restrict__ cU, const int* __restrict__ cA,
        int* __restrict__ pC, int* __restrict__ pU, int* __restrict__ pA,
        int nF, int nA, int nbF)
{
    __shared__ int sd[256];
    int b = blockIdx.x, t = threadIdx.x;
    const int* cnt; int* part; int n, lb;
    if (b < nbF)            { cnt = cC; part = pC; n = nF; lb = b; }
    else if (b < 2 * nbF)   { cnt = cU; part = pU; n = nF; lb = b - nbF; }
    else                    { cnt = cA; part = pA; n = nA; lb = b - 2 * nbF; }
    int base = lb * SCAN_CHUNK;
    int s = 0;
    for (int i = t; i < SCAN_CHUNK; i += 256) {
        int idx = base + i;
        s += (idx < n) ? cnt[idx] : 0;
    }
    sd[t] = s; __syncthreads();
    for (int st = 128; st > 0; st >>= 1) {
        if (t < st) sd[t] += sd[t + st];
        __syncthreads();
    }
    if (t == 0) part[lb] = sd[0];
}

__global__ void scan_small_all(int* pC, int* pU, int* pA, int nbF, int nbA)
{
    int t = threadIdx.x;
    if (t < 3) {
        int* p = (t == 0) ? pC : (t == 1) ? pU : pA;
        int nb = (t == 2) ? nbA : nbF;
        int run = 0;
        for (int i = 0; i < nb; ++i) { int v = p[i]; p[i] = run; run += v; }
    }
}

__global__ __launch_bounds__(256) void write_rowptr_all(
        const int* __restrict__ cC, const int* __restrict__ cU, const int* __restrict__ cA,
        const int* __restrict__ pC, const int* __restrict__ pU, const int* __restrict__ pA,
        int* __restrict__ rpC, int* __restrict__ rpU, int* __restrict__ rpA,
        int* __restrict__ nxC, int* __restrict__ nxU, int* __restrict__ nxA,
        int nF, int nA, int nbF, int E)
{
    __shared__ int sc[256];
    int b = blockIdx.x, t = threadIdx.x;
    const int* cnt; const int* part; int* rp; int* nx; int n, lb;
    if (b < nbF)            { cnt = cC; part = pC; rp = rpC; nx = nxC; n = nF; lb = b; }
    else if (b < 2 * nbF)   { cnt = cU; part = pU; rp = rpU; nx = nxU; n = nF; lb = b - nbF; }
    else                    { cnt = cA; part = pA; rp = rpA; nx = nxA; n = nA; lb = b - 2 * nbF; }
    int base = lb * SCAN_CHUNK;
    int loc[8]; int s = 0;
    #pragma unroll
    for (int i = 0; i < 8; ++i) {
        int idx = base + t * 8 + i;
        int v = (idx < n) ? cnt[idx] : 0;
        loc[i] = s; s += v;
    }
    sc[t] = s; __syncthreads();
    for (int st = 1; st < 256; st <<= 1) {
        int v = (t >= st) ? sc[t - st] : 0;
        __syncthreads();
        sc[t] += v;
        __syncthreads();
    }
    int off = part[lb] + (t > 0 ? sc[t - 1] : 0);
    #pragma unroll
    for (int i = 0; i < 8; ++i) {
        int idx = base + t * 8 + i;
        if (idx < n) { int v = off + loc[i]; rp[idx] = v; nx[idx] = v; }
    }
    if (lb == 0 && t == 0) rp[n] = E;
}

__global__ __launch_bounds__(256) void fill_all(
        const int* __restrict__ sC, const int* __restrict__ dC,
        const int* __restrict__ sU, const int* __restrict__ dU,
        const int* __restrict__ sA, const int* __restrict__ dA,
        int* __restrict__ nxC, int* __restrict__ nxU, int* __restrict__ nxA,
        int* __restrict__ colC, int* __restrict__ colU, int* __restrict__ colA, int E)
{
    int i = blockIdx.x * 256 + threadIdx.x;
    if (i >= 3 * E) return;
    int rel = i / E, e = i - rel * E;
    if (rel == 0)      { int pos = atomicAdd(&nxC[dC[e]], 1); colC[pos] = sC[e]; }
    else if (rel == 1) { int pos = atomicAdd(&nxU[dU[e]], 1); colU[pos] = sU[e]; }
    else               { int pos = atomicAdd(&nxA[dA[e]], 1); colA[pos] = sA[e]; }
}

// ---- h = relu(x @ W.T + b); W pre-transposed to (K,64) ----
template<int K>
__global__ __launch_bounds__(256) void proj_kernel(const float* __restrict__ x,
        const float* __restrict__ wt, const float* __restrict__ bias,
        float* __restrict__ hout, int nN)
{
    constexpr int KQ = K / 4;
    __shared__ float4 xs[64][KQ];
    const int i0 = blockIdx.x * 64;
    const int t = threadIdx.x;
    for (int idx = t; idx < 64 * KQ; idx += 256) {
        int n = idx / KQ, k4 = idx - n * KQ;
        float4 v = make_float4(0.f, 0.f, 0.f, 0.f);
        if (i0 + n < nN)
            v = *reinterpret_cast<const float4*>(x + (size_t)(i0 + n) * K + k4 * 4);
        xs[n][k4 ^ ((n >> 2) & 7)] = v;
    }
    __syncthreads();
    const int og = t & 15, ng = t >> 4;
    float4 acc[4];
    #pragma unroll
    for (int j = 0; j < 4; ++j) acc[j] = make_float4(0.f, 0.f, 0.f, 0.f);
    const float4* w4 = reinterpret_cast<const float4*>(wt);
    for (int k4 = 0; k4 < KQ; ++k4) {
        float4 w0 = w4[(4 * k4 + 0) * 16 + og];
        float4 w1 = w4[(4 * k4 + 1) * 16 + og];
        float4 w2 = w4[(4 * k4 + 2) * 16 + og];
        float4 w3 = w4[(4 * k4 + 3) * 16 + og];
        #pragma unroll
        for (int j = 0; j < 4; ++j) {
            int n = ng * 4 + j;
            float4 xv = xs[n][k4 ^ ((n >> 2) & 7)];
            fma4(acc[j], xv.x, w0); fma4(acc[j], xv.y, w1);
            fma4(acc[j], xv.z, w2); fma4(acc[j], xv.w, w3);
        }
    }
    float4 b = reinterpret_cast<const float4*>(bias)[og];
    #pragma unroll
    for (int j = 0; j < 4; ++j) {
        int node = i0 + ng * 4 + j;
        if (node < nN) {
            float4 o;
            o.x = fmaxf(acc[j].x + b.x, 0.f);
            o.y = fmaxf(acc[j].y + b.y, 0.f);
            o.z = fmaxf(acc[j].z + b.z, 0.f);
            o.w = fmaxf(acc[j].w + b.w, 0.f);
            *reinterpret_cast<float4*>(hout + (size_t)node * H + og * 4) = o;
        }
    }
}

// ---- fused func layer: gather(calls from hf_old) + gather(usedby from ha_old) + dense, ping-pong ----
__global__ __launch_bounds__(256) void layer_func_fused(
        const float* __restrict__ hf_old, const float* __restrict__ ha_old,
        float* __restrict__ hf_new,
        const int* __restrict__ rp_c, const int* __restrict__ col_c,
        const int* __restrict__ rp_u, const int* __restrict__ col_u,
        const float* __restrict__ wtr, const float* __restrict__ wtlc,
        const float* __restrict__ wtlu, const float* __restrict__ bias1,
        const float* __restrict__ bias2, int nN)
{
    __shared__ float4 hs[64][16], as_[64][16], us[64][16];
    const int i0 = blockIdx.x * 64;
    const int t = threadIdx.x;
    const int L = t & 15, nsub = t >> 4;   // 16 lanes per node; wave covers 4 nodes
    for (int p = 0; p < 4; ++p) {
        int n = p * 16 + nsub;
        int node = i0 + n;
        float4 hv = make_float4(0.f, 0.f, 0.f, 0.f), ac = hv, au = hv;
        if (node < nN) {
            hv = *reinterpret_cast<const float4*>(hf_old + (size_t)node * H + L * 4);
            int e0 = rp_c[node], e1 = rp_c[node + 1];
            for (int j = e0; j < e1; ++j) {
                int s = col_c[j];
                add4(ac, *reinterpret_cast<const float4*>(hf_old + (size_t)s * H + L * 4));
            }
            scl4(ac, 1.0f / (float)max(e1 - e0, 1));
            int u0 = rp_u[node], u1 = rp_u[node + 1];
            for (int j = u0; j < u1; ++j) {
                int s = col_u[j];
                add4(au, *reinterpret_cast<const float4*>(ha_old + (size_t)s * H + L * 4));
            }
            scl4(au, 1.0f / (float)max(u1 - u0, 1));
        }
        int sw = L ^ ((n >> 2) & 7);
        hs[n][sw] = hv; as_[n][sw] = ac; us[n][sw] = au;
    }
    __syncthreads();
    const int og = t & 15, ng = t >> 4;
    float4 acc[4];
    #pragma unroll
    for (int j = 0; j < 4; ++j) acc[j] = make_float4(0.f, 0.f, 0.f, 0.f);
    const float4* wr4 = reinterpret_cast<const float4*>(wtr);
    const float4* wc4 = reinterpret_cast<const float4*>(wtlc);
    const float4* wu4 = reinterpret_cast<const float4*>(wtlu);
    for (int k4 = 0; k4 < 16; ++k4) {
        float4 r0 = wr4[(4 * k4 + 0) * 16 + og], r1 = wr4[(4 * k4 + 1) * 16 + og];
        float4 r2 = wr4[(4 * k4 + 2) * 16 + og], r3 = wr4[(4 * k4 + 3) * 16 + og];
        float4 c0 = wc4[(4 * k4 + 0) * 16 + og], c1 = wc4[(4 * k4 + 1) * 16 + og];
        float4 c2 = wc4[(4 * k4 + 2) * 16 + og], c3 = wc4[(4 * k4 + 3) * 16 + og];
        float4 u0 = wu4[(4 * k4 + 0) * 16 + og], u1 = wu4[(4 * k4 + 1) * 16 + og];
        float4 u2 = wu4[(4 * k4 + 2) * 16 + og], u3 = wu4[(4 * k4 + 3) * 16 + og];
        #pragma unroll
        for (int j = 0; j < 4; ++j) {
            int n = ng * 4 + j;
            int sw = k4 ^ ((n >> 2) & 7);
            float4 xh = hs[n][sw], xa = as_[n][sw], xu = us[n][sw];
            fma4(acc[j], xh.x, r0); fma4(acc[j], xh.y, r1);
            fma4(acc[j], xh.z, r2); fma4(acc[j], xh.w, r3);
            fma4(acc[j], xa.x, c0); fma4(acc[j], xa.y, c1);
            fma4(acc[j], xa.z, c2); fma4(acc[j], xa.w, c3);
            fma4(acc[j], xu.x, u0); fma4(acc[j], xu.y, u1);
            fma4(acc[j], xu.z, u2); fma4(acc[j], xu.w, u3);
        }
    }
    float4 ba = reinterpret_cast<const float4*>(bias1)[og];
    float4 bb = reinterpret_cast<const float4*>(bias2)[og];
    float4 b = make_float4(ba.x + bb.x, ba.y + bb.y, ba.z + bb.z, ba.w + bb.w);
    #pragma unroll
    for (int j = 0; j < 4; ++j) {
        int node = i0 + ng * 4 + j;
        if (node < nN) {
            float4 o;
            o.x = fmaxf(acc[j].x + b.x, 0.f);
            o.y = fmaxf(acc[j].y + b.y, 0.f);
            o.z = fmaxf(acc[j].z + b.z, 0.f);
            o.w = fmaxf(acc[j].w + b.w, 0.f);
            *reinterpret_cast<float4*>(hf_new + (size_t)node * H + og * 4) = o;
        }
    }
}

// ---- fused api layer: gather(uses from hf_old) + dense, ping-pong ----
__global__ __launch_bounds__(256) void layer_api_fused(
        const float* __restrict__ ha_old, const float* __restrict__ hf_old,
        float* __restrict__ ha_new,
        const int* __restrict__ rp_a, const int* __restrict__ col_a,
        const float* __restrict__ wtr, const float* __restrict__ wtl,
        const float* __restrict__ bias1, int nN)
{
    __shared__ float4 hs[64][16], as_[64][16];
    const int i0 = blockIdx.x * 64;
    const int t = threadIdx.x;
    const int L = t & 15, nsub = t >> 4;
    for (int p = 0; p < 4; ++p) {
        int n = p * 16 + nsub;
        int node = i0 + n;
        float4 hv = make_float4(0.f, 0.f, 0.f, 0.f), av = hv;
        if (node < nN) {
            hv = *reinterpret_cast<const float4*>(ha_old + (size_t)node * H + L * 4);
            int e0 = rp_a[node], e1 = rp_a[node + 1];
            for (int j = e0; j < e1; ++j) {
                int s = col_a[j];
                add4(av, *reinterpret_cast<const float4*>(hf_old + (size_t)s * H + L * 4));
            }
            scl4(av, 1.0f / (float)max(e1 - e0, 1));
        }
        int sw = L ^ ((n >> 2) & 7);
        hs[n][sw] = hv; as_[n][sw] = av;
    }
    __syncthreads();
    const int og = t & 15, ng = t >> 4;
    float4 acc[4];
    #pragma unroll
    for (int j = 0; j < 4; ++j) acc[j] = make_float4(0.f, 0.f, 0.f, 0.f);
    const float4* wr4 = reinterpret_cast<const float4*>(wtr);
    const float4* wl4 = reinterpret_cast<const float4*>(wtl);
    for (int k4 = 0; k4 < 16; ++k4) {
        float4 r0 = wr4[(4 * k4 + 0) * 16 + og], r1 = wr4[(4 * k4 + 1) * 16 + og];
        float4 r2 = wr4[(4 * k4 + 2) * 16 + og], r3 = wr4[(4 * k4 + 3) * 16 + og];
        float4 c0 = wl4[(4 * k4 + 0) * 16 + og], c1 = wl4[(4 * k4 + 1) * 16 + og];
        float4 c2 = wl4[(4 * k4 + 2) * 16 + og], c3 = wl4[(4 * k4 + 3) * 16 + og];
        #pragma unroll
        for (int j = 0; j < 4; ++j) {
            int n = ng * 4 + j;
            int sw = k4 ^ ((n >> 2) & 7);
            float4 xh = hs[n][sw], xa = as_[n][sw];
            fma4(acc[j], xh.x, r0); fma4(acc[j], xh.y, r1);
            fma4(acc[j], xh.z, r2); fma4(acc[j], xh.w, r3);
            fma4(acc[j], xa.x, c0); fma4(acc[j], xa.y, c1);
            fma4(acc[j], xa.z, c2); fma4(acc[j], xa.w, c3);
        }
    }
    float4 b = reinterpret_cast<const float4*>(bias1)[og];
    #pragma unroll
    for (int j = 0; j < 4; ++j) {
        int node = i0 + ng * 4 + j;
        if (node < nN) {
            float4 o;
            o.x = fmaxf(acc[j].x + b.x, 0.f);
            o.y = fmaxf(acc[j].y + b.y, 0.f);
            o.z = fmaxf(acc[j].z + b.z, 0.f);
            o.w = fmaxf(acc[j].w + b.w, 0.f);
            *reinterpret_cast<float4*>(ha_new + (size_t)node * H + og * 4) = o;
        }
    }
}

__global__ __launch_bounds__(256) void pool_sum(const float* __restrict__ h,
        float* __restrict__ out, int nN)
{
    __shared__ float red[4][64];
    int c = threadIdx.x & 63, rl = threadIdx.x >> 6;
    float s = 0.f;
    for (int r = blockIdx.x * 4 + rl; r < nN; r += gridDim.x * 4)
        s += h[(size_t)r * H + c];
    red[rl][c] = s;
    __syncthreads();
    if (threadIdx.x < 64) {
        float v = red[0][c] + red[1][c] + red[2][c] + red[3][c];
        atomicAdd(&out[c], v);
    }
}

__global__ __launch_bounds__(128) void classifier_kernel(const float* __restrict__ pooled,
        const float* __restrict__ Wc1, const float* __restrict__ bc1,
        const float* __restrict__ Wc2, const float* __restrict__ bc2,
        float* __restrict__ out)
{
    __shared__ float ps[128];
    __shared__ float z1[64];
    int t = threadIdx.x;
    ps[t] = pooled[t] * (t < 64 ? (1.0f / N_FUNC) : (1.0f / N_API));
    __syncthreads();
    if (t < 64) {
        float a = bc1[t];
        for (int k = 0; k < 128; ++k) a = fmaf(ps[k], Wc1[t * 128 + k], a);
        z1[t] = fmaxf(a, 0.f);
    }
    __syncthreads();
    if (t < 2) {
        float a = bc2[t];
        for (int j = 0; j < 64; ++j) a = fmaf(z1[j], Wc2[t * 64 + j], a);
        out[t] = a;
    }
}

extern "C" void kernel_launch(void* const* d_in, const int* in_sizes, int n_in,
                              void* d_out, int out_size, void* d_ws, size_t ws_size,
                              hipStream_t stream)
{
    const float* x_func    = (const float*)d_in[0];
    const float* x_api     = (const float*)d_in[1];
    const float* w_in_func = (const float*)d_in[2];
    const float* b_in_func = (const float*)d_in[3];
    const float* w_in_api  = (const float*)d_in[4];
    const float* b_in_api  = (const float*)d_in[5];
    const float* Wl_calls  = (const float*)d_in[6];
    const float* bl_calls  = (const float*)d_in[7];
    const float* Wr_calls  = (const float*)d_in[8];
    const float* Wl_uses   = (const float*)d_in[9];
    const float* bl_uses   = (const float*)d_in[10];
    const float* Wr_uses   = (const float*)d_in[11];
    const float* Wl_usedby = (const float*)d_in[12];
    const float* bl_usedby = (const float*)d_in[13];
    const float* Wr_usedby = (const float*)d_in[14];
    const float* Wc1       = (const float*)d_in[15];
    const float* bc1       = (const float*)d_in[16];
    const float* Wc2       = (const float*)d_in[17];
    const float* bc2       = (const float*)d_in[18];
    const int*   ei_calls  = (const int*)d_in[19];
    const int*   ei_uses   = (const int*)d_in[20];
    const int*   ei_usedby = (const int*)d_in[21];
    const int E = in_sizes[19] / 2;

    float* ws = (float*)d_ws;
    size_t off = 0;
    float* hf0 = ws + off; off += (size_t)N_FUNC * H;
    float* hf1 = ws + off; off += (size_t)N_FUNC * H;
    float* ha0 = ws + off; off += (size_t)N_API * H;
    float* ha1 = ws + off; off += (size_t)N_API * H;
    float* prep = ws + off; off += 12288 + 10 * 4096;
    // int-typed scratch
    int* cntC = (int*)(ws + off); off += N_FUNC;   // cnt block + pooled contiguous for 1 memset
    int* cntU = (int*)(ws + off); off += N_FUNC;
    int* cntA = (int*)(ws + off); off += N_API;
    float* pooled = ws + off; off += 128;
    int* rpC = (int*)(ws + off); off += N_FUNC + 1;
    int* rpU = (int*)(ws + off); off += N_FUNC + 1;
    int* rpA = (int*)(ws + off); off += N_API + 1;
    int* nxC = (int*)(ws + off); off += N_FUNC + 1;
    int* nxU = (int*)(ws + off); off += N_FUNC + 1;
    int* nxA = (int*)(ws + off); off += N_API + 1;
    int* colC = (int*)(ws + off); off += E;
    int* colU = (int*)(ws + off); off += E;
    int* colA = (int*)(ws + off); off += E;
    int* partC = (int*)(ws + off); off += 128;
    int* partU = (int*)(ws + off); off += 128;
    int* partA = (int*)(ws + off); off += 128;

    const int nbF = (N_FUNC + SCAN_CHUNK - 1) / SCAN_CHUNK;  // 98
    const int nbA = (N_API + SCAN_CHUNK - 1) / SCAN_CHUNK;   // 25

    // zero counts + pooled (one contiguous memset)
    hipMemsetAsync(cntC, 0, (size_t)(2 * N_FUNC + N_API + 128) * sizeof(float), stream);

    prep_weights<<<(53248 + 255) / 256, 256, 0, stream>>>(
            w_in_func, w_in_api, Wl_calls, Wr_calls, Wl_uses, Wr_uses,
            Wl_usedby, Wr_usedby, prep);
    float* wt_in_func = prep;
    float* wt_in_api  = prep + 8192;
    float* wt_r[NLAYERS], *wt_lc[NLAYERS], *wt_lu[NLAYERS], *wt_luse[NLAYERS], *wt_ruse[NLAYERS];
    for (int l = 0; l < NLAYERS; ++l) {
        wt_r[l]    = prep + 12288 + (l * 5 + 0) * 4096;
        wt_lc[l]   = prep + 12288 + (l * 5 + 1) * 4096;
        wt_lu[l]   = prep + 12288 + (l * 5 + 2) * 4096;
        wt_luse[l] = prep + 12288 + (l * 5 + 3) * 4096;
        wt_ruse[l] = prep + 12288 + (l * 5 + 4) * 4096;
    }

    // CSR build (dst-indexed) for calls->func, usedby->func, uses->api
    count_all<<<(3 * E + 255) / 256, 256, 0, stream>>>(
            ei_calls + E, ei_usedby + E, ei_uses + E, cntC, cntU, cntA, E);
    block_sums_all<<<2 * nbF + nbA, 256, 0, stream>>>(
            cntC, cntU, cntA, partC, partU, partA, N_FUNC, N_API, nbF);
    scan_small_all<<<1, 64, 0, stream>>>(partC, partU, partA, nbF, nbA);
    write_rowptr_all<<<2 * nbF + nbA, 256, 0, stream>>>(
            cntC, cntU, cntA, partC, partU, partA,
            rpC, rpU, rpA, nxC, nxU, nxA, N_FUNC, N_API, nbF, E);
    fill_all<<<(3 * E + 255) / 256, 256, 0, stream>>>(
            ei_calls, ei_calls + E, ei_usedby, ei_usedby + E, ei_uses, ei_uses + E,
            nxC, nxU, nxA, colC, colU, colA, E);

    // input projections
    proj_kernel<128><<<(N_FUNC + 63) / 64, 256, 0, stream>>>(x_func, wt_in_func, b_in_func, hf0, N_FUNC);
    proj_kernel<64><<<(N_API + 63) / 64, 256, 0, stream>>>(x_api, wt_in_api, b_in_api, ha0, N_API);

    // layers (ping-pong)
    float* hf[2] = { hf0, hf1 };
    float* ha[2] = { ha0, ha1 };
    for (int l = 0; l < NLAYERS; ++l) {
        int cur = l & 1, nxt = cur ^ 1;
        layer_func_fused<<<(N_FUNC + 63) / 64, 256, 0, stream>>>(
                hf[cur], ha[cur], hf[nxt], rpC, colC, rpU, colU,
                wt_r[l], wt_lc[l], wt_lu[l], bl_calls + l * 64, bl_usedby + l * 64, N_FUNC);
        layer_api_fused<<<(N_API + 63) / 64, 256, 0, stream>>>(
                ha[cur], hf[cur], ha[nxt], rpA, colA,
                wt_ruse[l], wt_luse[l], bl_uses + l * 64, N_API);
    }

    pool_sum<<<512, 256, 0, stream>>>(hf[0], pooled, N_FUNC);
    pool_sum<<<512, 256, 0, stream>>>(ha[0], pooled + 64, N_API);
    classifier_kernel<<<1, 128, 0, stream>>>(pooled, Wc1, bc1, Wc2, bc2, (float*)d_out);
}

// Round 3
// 636.901 us; speedup vs baseline: 4.0363x; 1.1161x over previous
//
#include <hip/hip_runtime.h>

#define N_FUNC 200000
#define N_API  50000
#define H      64
#define NLAYERS 2
#define SCAN_CHUNK 2048
#define NBF 3125   // N_FUNC/64 exact
#define NBA 782    // ceil(N_API/64)

__device__ __forceinline__ void fma4(float4& a, float s, float4 w) {
    a.x = fmaf(s, w.x, a.x); a.y = fmaf(s, w.y, a.y);
    a.z = fmaf(s, w.z, a.z); a.w = fmaf(s, w.w, a.w);
}
__device__ __forceinline__ void add4(float4& a, float4 v) {
    a.x += v.x; a.y += v.y; a.z += v.z; a.w += v.w;
}
__device__ __forceinline__ void scl4(float4& a, float s) {
    a.x *= s; a.y *= s; a.z *= s; a.w *= s;
}

// ---- weight prep: all transposes (+Wr combine) in ONE launch ----
__global__ __launch_bounds__(256) void prep_weights(
        const float* __restrict__ w_in_func, const float* __restrict__ w_in_api,
        const float* __restrict__ Wl_calls, const float* __restrict__ Wr_calls,
        const float* __restrict__ Wl_uses,  const float* __restrict__ Wr_uses,
        const float* __restrict__ Wl_usedby,const float* __restrict__ Wr_usedby,
        float* __restrict__ out)
{
    int idx = blockIdx.x * 256 + threadIdx.x;
    if (idx < 8192) {
        int k = idx >> 6, o = idx & 63;
        out[idx] = w_in_func[o * 128 + k];
    } else if (idx < 12288) {
        int r = idx - 8192; int k = r >> 6, o = r & 63;
        out[idx] = w_in_api[o * 64 + k];
    } else if (idx < 12288 + 10 * 4096) {
        int r = idx - 12288;
        int m = r >> 12, w = r & 4095;
        int k = w >> 6, o = w & 63;
        int l = m / 5, which = m - 5 * l;
        const float* A; const float* B = nullptr;
        if (which == 0)      { A = Wr_calls  + l * 4096; B = Wr_usedby + l * 4096; }
        else if (which == 1)   A = Wl_calls  + l * 4096;
        else if (which == 2)   A = Wl_usedby + l * 4096;
        else if (which == 3)   A = Wl_uses   + l * 4096;
        else                   A = Wr_uses   + l * 4096;
        float v = A[o * 64 + k];
        if (B) v += B[o * 64 + k];
        out[idx] = v;
    }
}

// ---- CSR build (3 relations batched) ----
__global__ __launch_bounds__(256) void count_all(
        const int* __restrict__ dC, const int* __restrict__ dU, const int* __restrict__ dA,
        int* __restrict__ cC, int* __restrict__ cU, int* __restrict__ cA, int E)
{
    int i = blockIdx.x * 256 + threadIdx.x;
    if (i >= 3 * E) return;
    int rel = i / E, e = i - rel * E;
    if (rel == 0)      atomicAdd(&cC[dC[e]], 1);
    else if (rel == 1) atomicAdd(&cU[dU[e]], 1);
    else               atomicAdd(&cA[dA[e]], 1);
}

__global__ __launch_bounds__(256) void block_sums_all(
        const int* __restrict__ cC, const int* __restrict__ cU, const int* __restrict__ cA,
        int* __restrict__ pC, int* __restrict__ pU, int* __restrict__ pA,
        int nF, int nA, int nbF)
{
    __shared__ int sd[256];
    int b = blockIdx.x, t = threadIdx.x;
    const int* cnt; int* part; int n, lb;
    if (b < nbF)            { cnt = cC; part = pC; n = nF; lb = b; }
    else if (b < 2 * nbF)   { cnt = cU; part = pU; n = nF; lb = b - nbF; }
    else                    { cnt = cA; part = pA; n = nA; lb = b - 2 * nbF; }
    int base = lb * SCAN_CHUNK;
    int s = 0;
    for (int i = t; i < SCAN_CHUNK; i += 256) {
        int idx = base + i;
        s += (idx < n) ? cnt[idx] : 0;
    }
    sd[t] = s; __syncthreads();
    for (int st = 128; st > 0; st >>= 1) {
        if (t < st) sd[t] += sd[t + st];
        __syncthreads();
    }
    if (t == 0) part[lb] = sd[0];
}

__global__ void scan_small_all(int* pC, int* pU, int* pA, int nbF, int nbA)
{
    int t = threadIdx.x;
    if (t < 3) {
        int* p = (t == 0) ? pC : (t == 1) ? pU : pA;
        int nb = (t == 2) ? nbA : nbF;
        int run = 0;
        for (int i = 0; i < nb; ++i) { int v = p[i]; p[i] = run; run += v; }
    }
}

__global__ __launch_bounds__(256) void write_rowptr_all(
        const int* __restrict__ cC, const int* __restrict__ cU, const int* __restrict__ cA,
        const int* __restrict__ pC, const int* __restrict__ pU, const int* __restrict__ pA,
        int* __restrict__ rpC, int* __restrict__ rpU, int* __restrict__ rpA,
        int* __restrict__ nxC, int* __restrict__ nxU, int* __restrict__ nxA,
        int nF, int nA, int nbF, int E)
{
    __shared__ int sc[256];
    int b = blockIdx.x, t = threadIdx.x;
    const int* cnt; const int* part; int* rp; int* nx; int n, lb;
    if (b < nbF)            { cnt = cC; part = pC; rp = rpC; nx = nxC; n = nF; lb = b; }
    else if (b < 2 * nbF)   { cnt = cU; part = pU; rp = rpU; nx = nxU; n = nF; lb = b - nbF; }
    else                    { cnt = cA; part = pA; rp = rpA; nx = nxA; n = nA; lb = b - 2 * nbF; }
    int base = lb * SCAN_CHUNK;
    int loc[8]; int s = 0;
    #pragma unroll
    for (int i = 0; i < 8; ++i) {
        int idx = base + t * 8 + i;
        int v = (idx < n) ? cnt[idx] : 0;
        loc[i] = s; s += v;
    }
    sc[t] = s; __syncthreads();
    for (int st = 1; st < 256; st <<= 1) {
        int v = (t >= st) ? sc[t - st] : 0;
        __syncthreads();
        sc[t] += v;
        __syncthreads();
    }
    int off = part[lb] + (t > 0 ? sc[t - 1] : 0);
    #pragma unroll
    for (int i = 0; i < 8; ++i) {
        int idx = base + t * 8 + i;
        if (idx < n) { int v = off + loc[i]; rp[idx] = v; nx[idx] = v; }
    }
    if (lb == 0 && t == 0) rp[n] = E;
}

__global__ __launch_bounds__(256) void fill_all(
        const int* __restrict__ sC, const int* __restrict__ dC,
        const int* __restrict__ sU, const int* __restrict__ dU,
        const int* __restrict__ sA, const int* __restrict__ dA,
        int* __restrict__ nxC, int* __restrict__ nxU, int* __restrict__ nxA,
        int* __restrict__ colC, int* __restrict__ colU, int* __restrict__ colA, int E)
{
    int i = blockIdx.x * 256 + threadIdx.x;
    if (i >= 3 * E) return;
    int rel = i / E, e = i - rel * E;
    if (rel == 0)      { int pos = atomicAdd(&nxC[dC[e]], 1); colC[pos] = sC[e]; }
    else if (rel == 1) { int pos = atomicAdd(&nxU[dU[e]], 1); colU[pos] = sU[e]; }
    else               { int pos = atomicAdd(&nxA[dA[e]], 1); colA[pos] = sA[e]; }
}

// ---- fused projections: h = relu(x @ W.T + b), W pre-transposed (K,64) ----
template<int K>
__device__ __forceinline__ void proj_body(const float* __restrict__ x,
        const float* __restrict__ wt, const float* __restrict__ bias,
        float* __restrict__ hout, int i0, int nN, float4* smem)
{
    constexpr int KQ = K / 4;
    const int t = threadIdx.x;
    for (int idx = t; idx < 64 * KQ; idx += 256) {
        int n = idx / KQ, k4 = idx - n * KQ;
        float4 v = make_float4(0.f, 0.f, 0.f, 0.f);
        if (i0 + n < nN)
            v = *reinterpret_cast<const float4*>(x + (size_t)(i0 + n) * K + k4 * 4);
        smem[n * KQ + (k4 ^ ((n >> 2) & 7))] = v;
    }
    __syncthreads();
    const int og = t & 15, ng = t >> 4;
    float4 acc[4];
    #pragma unroll
    for (int j = 0; j < 4; ++j) acc[j] = make_float4(0.f, 0.f, 0.f, 0.f);
    const float4* w4 = reinterpret_cast<const float4*>(wt);
    for (int k4 = 0; k4 < KQ; ++k4) {
        float4 w0 = w4[(4 * k4 + 0) * 16 + og];
        float4 w1 = w4[(4 * k4 + 1) * 16 + og];
        float4 w2 = w4[(4 * k4 + 2) * 16 + og];
        float4 w3 = w4[(4 * k4 + 3) * 16 + og];
        #pragma unroll
        for (int j = 0; j < 4; ++j) {
            int n = ng * 4 + j;
            float4 xv = smem[n * KQ + (k4 ^ ((n >> 2) & 7))];
            fma4(acc[j], xv.x, w0); fma4(acc[j], xv.y, w1);
            fma4(acc[j], xv.z, w2); fma4(acc[j], xv.w, w3);
        }
    }
    float4 b = reinterpret_cast<const float4*>(bias)[og];
    #pragma unroll
    for (int j = 0; j < 4; ++j) {
        int node = i0 + ng * 4 + j;
        if (node < nN) {
            float4 o;
            o.x = fmaxf(acc[j].x + b.x, 0.f);
            o.y = fmaxf(acc[j].y + b.y, 0.f);
            o.z = fmaxf(acc[j].z + b.z, 0.f);
            o.w = fmaxf(acc[j].w + b.w, 0.f);
            *reinterpret_cast<float4*>(hout + (size_t)node * H + og * 4) = o;
        }
    }
}

__global__ __launch_bounds__(256) void proj_both(
        const float* __restrict__ xf, const float* __restrict__ wtf,
        const float* __restrict__ bf, float* __restrict__ hf,
        const float* __restrict__ xa, const float* __restrict__ wta,
        const float* __restrict__ ba, float* __restrict__ ha)
{
    __shared__ float4 smem[64 * 32];
    int b = blockIdx.x;
    if (b < NBF) proj_body<128>(xf, wtf, bf, hf, b * 64, N_FUNC, smem);
    else         proj_body<64>(xa, wta, ba, ha, (b - NBF) * 64, N_API, smem);
}

// ---- fused layer (func blocks + api blocks in one grid) ----
// func: hf_new = relu(mean_calls(hf_old)@Wlc + mean_usedby(ha_old)@Wlu + hf_old@(Wrc+Wru) + b)
// api:  ha_new = relu(mean_uses(hf_old)@Wluse + ha_old@Wruse + b)
__global__ __launch_bounds__(256, 4) void layer_both(
        const float* __restrict__ hf_old, const float* __restrict__ ha_old,
        float* __restrict__ hf_new, float* __restrict__ ha_new,
        const int* __restrict__ rpC, const int* __restrict__ colC,
        const int* __restrict__ rpU, const int* __restrict__ colU,
        const int* __restrict__ rpA, const int* __restrict__ colA,
        const float* __restrict__ wtr, const float* __restrict__ wtlc,
        const float* __restrict__ wtlu,
        const float* __restrict__ wtruse, const float* __restrict__ wtluse,
        const float* __restrict__ bias_c, const float* __restrict__ bias_u,
        const float* __restrict__ bias_a)
{
    __shared__ float4 as_[64][16], us[64][16];
    const int b = blockIdx.x;
    const int t = threadIdx.x;
    const int L = t & 15, nsub = t >> 4;

    if (b < NBF) {
        const int i0 = b * 64;
        float4 ac[4], au[4];
        int jc[4], ec[4], ju[4], eu[4], dc[4], du[4];
        #pragma unroll
        for (int p = 0; p < 4; ++p) {
            int node = i0 + p * 16 + nsub;
            ac[p] = make_float4(0.f, 0.f, 0.f, 0.f);
            au[p] = make_float4(0.f, 0.f, 0.f, 0.f);
            jc[p] = rpC[node]; ec[p] = rpC[node + 1];
            ju[p] = rpU[node]; eu[p] = rpU[node + 1];
            dc[p] = ec[p] - jc[p]; du[p] = eu[p] - ju[p];
        }
        // 4-way interleaved gather (calls, from hf_old)
        while (jc[0] < ec[0] || jc[1] < ec[1] || jc[2] < ec[2] || jc[3] < ec[3]) {
            float4 v[4]; bool a[4];
            #pragma unroll
            for (int p = 0; p < 4; ++p) {
                a[p] = jc[p] < ec[p];
                if (a[p]) {
                    int s = colC[jc[p]++];
                    v[p] = *reinterpret_cast<const float4*>(hf_old + (size_t)s * H + L * 4);
                }
            }
            #pragma unroll
            for (int p = 0; p < 4; ++p) if (a[p]) add4(ac[p], v[p]);
        }
        // 4-way interleaved gather (usedby, from ha_old)
        while (ju[0] < eu[0] || ju[1] < eu[1] || ju[2] < eu[2] || ju[3] < eu[3]) {
            float4 v[4]; bool a[4];
            #pragma unroll
            for (int p = 0; p < 4; ++p) {
                a[p] = ju[p] < eu[p];
                if (a[p]) {
                    int s = colU[ju[p]++];
                    v[p] = *reinterpret_cast<const float4*>(ha_old + (size_t)s * H + L * 4);
                }
            }
            #pragma unroll
            for (int p = 0; p < 4; ++p) if (a[p]) add4(au[p], v[p]);
        }
        #pragma unroll
        for (int p = 0; p < 4; ++p) {
            int n = p * 16 + nsub;
            int sw = L ^ ((n >> 2) & 7);
            scl4(ac[p], 1.0f / (float)max(dc[p], 1));
            scl4(au[p], 1.0f / (float)max(du[p], 1));
            as_[n][sw] = ac[p]; us[n][sw] = au[p];
        }
        __syncthreads();
        const int og = t & 15, ng = t >> 4;
        float4 acc[4];
        #pragma unroll
        for (int j = 0; j < 4; ++j) acc[j] = make_float4(0.f, 0.f, 0.f, 0.f);
        const float4* wr4 = reinterpret_cast<const float4*>(wtr);
        const float4* wc4 = reinterpret_cast<const float4*>(wtlc);
        const float4* wu4 = reinterpret_cast<const float4*>(wtlu);
        for (int k4 = 0; k4 < 16; ++k4) {
            float4 r0 = wr4[(4 * k4 + 0) * 16 + og], r1 = wr4[(4 * k4 + 1) * 16 + og];
            float4 r2 = wr4[(4 * k4 + 2) * 16 + og], r3 = wr4[(4 * k4 + 3) * 16 + og];
            float4 c0 = wc4[(4 * k4 + 0) * 16 + og], c1 = wc4[(4 * k4 + 1) * 16 + og];
            float4 c2 = wc4[(4 * k4 + 2) * 16 + og], c3 = wc4[(4 * k4 + 3) * 16 + og];
            float4 u0 = wu4[(4 * k4 + 0) * 16 + og], u1 = wu4[(4 * k4 + 1) * 16 + og];
            float4 u2 = wu4[(4 * k4 + 2) * 16 + og], u3 = wu4[(4 * k4 + 3) * 16 + og];
            #pragma unroll
            for (int j = 0; j < 4; ++j) {
                int n = ng * 4 + j;
                int sw = k4 ^ ((n >> 2) & 7);
                float4 xh = *reinterpret_cast<const float4*>(hf_old + (size_t)(i0 + n) * H + k4 * 4);
                float4 xa = as_[n][sw], xu = us[n][sw];
                fma4(acc[j], xh.x, r0); fma4(acc[j], xh.y, r1);
                fma4(acc[j], xh.z, r2); fma4(acc[j], xh.w, r3);
                fma4(acc[j], xa.x, c0); fma4(acc[j], xa.y, c1);
                fma4(acc[j], xa.z, c2); fma4(acc[j], xa.w, c3);
                fma4(acc[j], xu.x, u0); fma4(acc[j], xu.y, u1);
                fma4(acc[j], xu.z, u2); fma4(acc[j], xu.w, u3);
            }
        }
        float4 ba = reinterpret_cast<const float4*>(bias_c)[og];
        float4 bb = reinterpret_cast<const float4*>(bias_u)[og];
        float4 bv = make_float4(ba.x + bb.x, ba.y + bb.y, ba.z + bb.z, ba.w + bb.w);
        #pragma unroll
        for (int j = 0; j < 4; ++j) {
            int node = i0 + ng * 4 + j;
            float4 o;
            o.x = fmaxf(acc[j].x + bv.x, 0.f);
            o.y = fmaxf(acc[j].y + bv.y, 0.f);
            o.z = fmaxf(acc[j].z + bv.z, 0.f);
            o.w = fmaxf(acc[j].w + bv.w, 0.f);
            *reinterpret_cast<float4*>(hf_new + (size_t)node * H + og * 4) = o;
        }
    } else {
        const int i0 = (b - NBF) * 64;
        float4 av[4];
        int ja[4], ea[4], da[4];
        #pragma unroll
        for (int p = 0; p < 4; ++p) {
            int node = i0 + p * 16 + nsub;
            av[p] = make_float4(0.f, 0.f, 0.f, 0.f);
            if (node < N_API) { ja[p] = rpA[node]; ea[p] = rpA[node + 1]; }
            else { ja[p] = 0; ea[p] = 0; }
            da[p] = ea[p] - ja[p];
        }
        while (ja[0] < ea[0] || ja[1] < ea[1] || ja[2] < ea[2] || ja[3] < ea[3]) {
            float4 v[4]; bool a[4];
            #pragma unroll
            for (int p = 0; p < 4; ++p) {
                a[p] = ja[p] < ea[p];
                if (a[p]) {
                    int s = colA[ja[p]++];
                    v[p] = *reinterpret_cast<const float4*>(hf_old + (size_t)s * H + L * 4);
                }
            }
            #pragma unroll
            for (int p = 0; p < 4; ++p) if (a[p]) add4(av[p], v[p]);
        }
        #pragma unroll
        for (int p = 0; p < 4; ++p) {
            int n = p * 16 + nsub;
            int sw = L ^ ((n >> 2) & 7);
            scl4(av[p], 1.0f / (float)max(da[p], 1));
            as_[n][sw] = av[p];
        }
        __syncthreads();
        const int og = t & 15, ng = t >> 4;
        float4 acc[4];
        #pragma unroll
        for (int j = 0; j < 4; ++j) acc[j] = make_float4(0.f, 0.f, 0.f, 0.f);
        const float4* wr4 = reinterpret_cast<const float4*>(wtruse);
        const float4* wl4 = reinterpret_cast<const float4*>(wtluse);
        for (int k4 = 0; k4 < 16; ++k4) {
            float4 r0 = wr4[(4 * k4 + 0) * 16 + og], r1 = wr4[(4 * k4 + 1) * 16 + og];
            float4 r2 = wr4[(4 * k4 + 2) * 16 + og], r3 = wr4[(4 * k4 + 3) * 16 + og];
            float4 c0 = wl4[(4 * k4 + 0) * 16 + og], c1 = wl4[(4 * k4 + 1) * 16 + og];
            float4 c2 = wl4[(4 * k4 + 2) * 16 + og], c3 = wl4[(4 * k4 + 3) * 16 + og];
            #pragma unroll
            for (int j = 0; j < 4; ++j) {
                int n = ng * 4 + j;
                int node = i0 + n;
                int sw = k4 ^ ((n >> 2) & 7);
                float4 xh = make_float4(0.f, 0.f, 0.f, 0.f);
                if (node < N_API)
                    xh = *reinterpret_cast<const float4*>(ha_old + (size_t)node * H + k4 * 4);
                float4 xa = as_[n][sw];
                fma4(acc[j], xh.x, r0); fma4(acc[j], xh.y, r1);
                fma4(acc[j], xh.z, r2); fma4(acc[j], xh.w, r3);
                fma4(acc[j], xa.x, c0); fma4(acc[j], xa.y, c1);
                fma4(acc[j], xa.z, c2); fma4(acc[j], xa.w, c3);
            }
        }
        float4 bv = reinterpret_cast<const float4*>(bias_a)[og];
        #pragma unroll
        for (int j = 0; j < 4; ++j) {
            int node = i0 + ng * 4 + j;
            if (node < N_API) {
                float4 o;
                o.x = fmaxf(acc[j].x + bv.x, 0.f);
                o.y = fmaxf(acc[j].y + bv.y, 0.f);
                o.z = fmaxf(acc[j].z + bv.z, 0.f);
                o.w = fmaxf(acc[j].w + bv.w, 0.f);
                *reinterpret_cast<float4*>(ha_new + (size_t)node * H + og * 4) = o;
            }
        }
    }
}

__global__ __launch_bounds__(256) void pool_both(const float* __restrict__ hf,
        const float* __restrict__ ha, float* __restrict__ pooled)
{
    __shared__ float red[4][64];
    const float* h; float* out; int nN, bid, nb;
    if (blockIdx.x < 512) { h = hf; out = pooled;      nN = N_FUNC; bid = blockIdx.x;       nb = 512; }
    else                  { h = ha; out = pooled + 64; nN = N_API;  bid = blockIdx.x - 512; nb = 128; }
    int c = threadIdx.x & 63, rl = threadIdx.x >> 6;
    float s = 0.f;
    for (int r = bid * 4 + rl; r < nN; r += nb * 4)
        s += h[(size_t)r * H + c];
    red[rl][c] = s;
    __syncthreads();
    if (threadIdx.x < 64)
        atomicAdd(&out[c], red[0][c] + red[1][c] + red[2][c] + red[3][c]);
}

__global__ __launch_bounds__(128) void classifier_kernel(const float* __restrict__ pooled,
        const float* __restrict__ Wc1, const float* __restrict__ bc1,
        const float* __restrict__ Wc2, const float* __restrict__ bc2,
        float* __restrict__ out)
{
    __shared__ float ps[128];
    __shared__ float z1[64];
    int t = threadIdx.x;
    ps[t] = pooled[t] * (t < 64 ? (1.0f / N_FUNC) : (1.0f / N_API));
    __syncthreads();
    if (t < 64) {
        float a = bc1[t];
        for (int k = 0; k < 128; ++k) a = fmaf(ps[k], Wc1[t * 128 + k], a);
        z1[t] = fmaxf(a, 0.f);
    }
    __syncthreads();
    if (t < 2) {
        float a = bc2[t];
        for (int j = 0; j < 64; ++j) a = fmaf(z1[j], Wc2[t * 64 + j], a);
        out[t] = a;
    }
}

extern "C" void kernel_launch(void* const* d_in, const int* in_sizes, int n_in,
                              void* d_out, int out_size, void* d_ws, size_t ws_size,
                              hipStream_t stream)
{
    const float* x_func    = (const float*)d_in[0];
    const float* x_api     = (const float*)d_in[1];
    const float* w_in_func = (const float*)d_in[2];
    const float* b_in_func = (const float*)d_in[3];
    const float* w_in_api  = (const float*)d_in[4];
    const float* b_in_api  = (const float*)d_in[5];
    const float* Wl_calls  = (const float*)d_in[6];
    const float* bl_calls  = (const float*)d_in[7];
    const float* Wr_calls  = (const float*)d_in[8];
    const float* Wl_uses   = (const float*)d_in[9];
    const float* bl_uses   = (const float*)d_in[10];
    const float* Wr_uses   = (const float*)d_in[11];
    const float* Wl_usedby = (const float*)d_in[12];
    const float* bl_usedby = (const float*)d_in[13];
    const float* Wr_usedby = (const float*)d_in[14];
    const float* Wc1       = (const float*)d_in[15];
    const float* bc1       = (const float*)d_in[16];
    const float* Wc2       = (const float*)d_in[17];
    const float* bc2       = (const float*)d_in[18];
    const int*   ei_calls  = (const int*)d_in[19];
    const int*   ei_uses   = (const int*)d_in[20];
    const int*   ei_usedby = (const int*)d_in[21];
    const int E = in_sizes[19] / 2;

    float* ws = (float*)d_ws;
    size_t off = 0;
    float* hf0 = ws + off; off += (size_t)N_FUNC * H;
    float* hf1 = ws + off; off += (size_t)N_FUNC * H;
    float* ha0 = ws + off; off += (size_t)N_API * H;
    float* ha1 = ws + off; off += (size_t)N_API * H;
    float* prep = ws + off; off += 12288 + 10 * 4096;
    int* cntC = (int*)(ws + off); off += N_FUNC;   // cnt block + pooled contiguous for 1 memset
    int* cntU = (int*)(ws + off); off += N_FUNC;
    int* cntA = (int*)(ws + off); off += N_API;
    float* pooled = ws + off; off += 128;
    int* rpC = (int*)(ws + off); off += N_FUNC + 1;
    int* rpU = (int*)(ws + off); off += N_FUNC + 1;
    int* rpA = (int*)(ws + off); off += N_API + 1;
    int* nxC = (int*)(ws + off); off += N_FUNC + 1;
    int* nxU = (int*)(ws + off); off += N_FUNC + 1;
    int* nxA = (int*)(ws + off); off += N_API + 1;
    int* colC = (int*)(ws + off); off += E;
    int* colU = (int*)(ws + off); off += E;
    int* colA = (int*)(ws + off); off += E;
    int* partC = (int*)(ws + off); off += 128;
    int* partU = (int*)(ws + off); off += 128;
    int* partA = (int*)(ws + off); off += 128;

    const int nbF = (N_FUNC + SCAN_CHUNK - 1) / SCAN_CHUNK;  // 98
    const int nbA = (N_API + SCAN_CHUNK - 1) / SCAN_CHUNK;   // 25

    hipMemsetAsync(cntC, 0, (size_t)(2 * N_FUNC + N_API + 128) * sizeof(float), stream);

    prep_weights<<<(53248 + 255) / 256, 256, 0, stream>>>(
            w_in_func, w_in_api, Wl_calls, Wr_calls, Wl_uses, Wr_uses,
            Wl_usedby, Wr_usedby, prep);
    float* wt_in_func = prep;
    float* wt_in_api  = prep + 8192;
    float* wt_r[NLAYERS], *wt_lc[NLAYERS], *wt_lu[NLAYERS], *wt_luse[NLAYERS], *wt_ruse[NLAYERS];
    for (int l = 0; l < NLAYERS; ++l) {
        wt_r[l]    = prep + 12288 + (l * 5 + 0) * 4096;
        wt_lc[l]   = prep + 12288 + (l * 5 + 1) * 4096;
        wt_lu[l]   = prep + 12288 + (l * 5 + 2) * 4096;
        wt_luse[l] = prep + 12288 + (l * 5 + 3) * 4096;
        wt_ruse[l] = prep + 12288 + (l * 5 + 4) * 4096;
    }

    count_all<<<(3 * E + 255) / 256, 256, 0, stream>>>(
            ei_calls + E, ei_usedby + E, ei_uses + E, cntC, cntU, cntA, E);
    block_sums_all<<<2 * nbF + nbA, 256, 0, stream>>>(
            cntC, cntU, cntA, partC, partU, partA, N_FUNC, N_API, nbF);
    scan_small_all<<<1, 64, 0, stream>>>(partC, partU, partA, nbF, nbA);
    write_rowptr_all<<<2 * nbF + nbA, 256, 0, stream>>>(
            cntC, cntU, cntA, partC, partU, partA,
            rpC, rpU, rpA, nxC, nxU, nxA, N_FUNC, N_API, nbF, E);
    fill_all<<<(3 * E + 255) / 256, 256, 0, stream>>>(
            ei_calls, ei_calls + E, ei_usedby, ei_usedby + E, ei_uses, ei_uses + E,
            nxC, nxU, nxA, colC, colU, colA, E);

    proj_both<<<NBF + NBA, 256, 0, stream>>>(
            x_func, wt_in_func, b_in_func, hf0,
            x_api, wt_in_api, b_in_api, ha0);

    float* hf[2] = { hf0, hf1 };
    float* ha[2] = { ha0, ha1 };
    for (int l = 0; l < NLAYERS; ++l) {
        int cur = l & 1, nxt = cur ^ 1;
        layer_both<<<NBF + NBA, 256, 0, stream>>>(
                hf[cur], ha[cur], hf[nxt], ha[nxt],
                rpC, colC, rpU, colU, rpA, colA,
                wt_r[l], wt_lc[l], wt_lu[l], wt_ruse[l], wt_luse[l],
                bl_calls + l * 64, bl_usedby + l * 64, bl_uses + l * 64);
    }

    pool_both<<<640, 256, 0, stream>>>(hf[0], ha[0], pooled);
    classifier_kernel<<<1, 128, 0, stream>>>(pooled, Wc1, bc1, Wc2, bc2, (float*)d_out);
}

// Round 4
// 612.246 us; speedup vs baseline: 4.1988x; 1.0403x over previous
//
#include <hip/hip_runtime.h>

#define N_FUNC 200000
#define N_API  50000
#define H      64
#define NLAYERS 2
#define SCAN_CHUNK 2048
#define NBF 3125   // N_FUNC/64 exact
#define NBA 782    // ceil(N_API/64)
#define PREP_BLOCKS 208  // ceil(53248/256)

__device__ __forceinline__ void fma4(float4& a, float s, float4 w) {
    a.x = fmaf(s, w.x, a.x); a.y = fmaf(s, w.y, a.y);
    a.z = fmaf(s, w.z, a.z); a.w = fmaf(s, w.w, a.w);
}
__device__ __forceinline__ void add4(float4& a, float4 v) {
    a.x += v.x; a.y += v.y; a.z += v.z; a.w += v.w;
}
__device__ __forceinline__ void scl4(float4& a, float s) {
    a.x *= s; a.y *= s; a.z *= s; a.w *= s;
}

// ---- K1: weight prep (208 blocks) + edge histogram (rest) in one launch ----
__global__ __launch_bounds__(256) void prep_and_count(
        const float* __restrict__ w_in_func, const float* __restrict__ w_in_api,
        const float* __restrict__ Wl_calls, const float* __restrict__ Wr_calls,
        const float* __restrict__ Wl_uses,  const float* __restrict__ Wr_uses,
        const float* __restrict__ Wl_usedby,const float* __restrict__ Wr_usedby,
        float* __restrict__ out,
        const int* __restrict__ dC, const int* __restrict__ dU, const int* __restrict__ dA,
        int* __restrict__ cC, int* __restrict__ cU, int* __restrict__ cA, int E)
{
    int b = blockIdx.x;
    if (b < PREP_BLOCKS) {
        int idx = b * 256 + threadIdx.x;
        if (idx < 8192) {
            int k = idx >> 6, o = idx & 63;
            out[idx] = w_in_func[o * 128 + k];
        } else if (idx < 12288) {
            int r = idx - 8192; int k = r >> 6, o = r & 63;
            out[idx] = w_in_api[o * 64 + k];
        } else if (idx < 12288 + 10 * 4096) {
            int r = idx - 12288;
            int m = r >> 12, w = r & 4095;
            int k = w >> 6, o = w & 63;
            int l = m / 5, which = m - 5 * l;
            const float* A; const float* B = nullptr;
            if (which == 0)      { A = Wr_calls  + l * 4096; B = Wr_usedby + l * 4096; }
            else if (which == 1)   A = Wl_calls  + l * 4096;
            else if (which == 2)   A = Wl_usedby + l * 4096;
            else if (which == 3)   A = Wl_uses   + l * 4096;
            else                   A = Wr_uses   + l * 4096;
            float v = A[o * 64 + k];
            if (B) v += B[o * 64 + k];
            out[idx] = v;
        }
    } else {
        int i = (b - PREP_BLOCKS) * 256 + threadIdx.x;
        if (i >= 3 * E) return;
        int rel = i / E, e = i - rel * E;
        if (rel == 0)      atomicAdd(&cC[dC[e]], 1);
        else if (rel == 1) atomicAdd(&cU[dU[e]], 1);
        else               atomicAdd(&cA[dA[e]], 1);
    }
}

__global__ __launch_bounds__(256) void block_sums_all(
        const int* __restrict__ cC, const int* __restrict__ cU, const int* __restrict__ cA,
        int* __restrict__ pC, int* __restrict__ pU, int* __restrict__ pA,
        int nF, int nA, int nbF)
{
    __shared__ int sd[256];
    int b = blockIdx.x, t = threadIdx.x;
    const int* cnt; int* part; int n, lb;
    if (b < nbF)            { cnt = cC; part = pC; n = nF; lb = b; }
    else if (b < 2 * nbF)   { cnt = cU; part = pU; n = nF; lb = b - nbF; }
    else                    { cnt = cA; part = pA; n = nA; lb = b - 2 * nbF; }
    int base = lb * SCAN_CHUNK;
    int s = 0;
    for (int i = t; i < SCAN_CHUNK; i += 256) {
        int idx = base + i;
        s += (idx < n) ? cnt[idx] : 0;
    }
    sd[t] = s; __syncthreads();
    for (int st = 128; st > 0; st >>= 1) {
        if (t < st) sd[t] += sd[t + st];
        __syncthreads();
    }
    if (t == 0) part[lb] = sd[0];
}

// wave-parallel scan of partial sums (nb <= 128 per relation), 3 waves
__global__ __launch_bounds__(192) void scan_small_all(int* pC, int* pU, int* pA, int nbF, int nbA)
{
    int w = threadIdx.x >> 6, lane = threadIdx.x & 63;
    int* p = (w == 0) ? pC : (w == 1) ? pU : pA;
    int nb = (w == 2) ? nbA : nbF;
    int o0 = (lane < nb) ? p[lane] : 0;
    int o1 = (64 + lane < nb) ? p[64 + lane] : 0;
    int v0 = o0, v1 = o1;
    for (int off = 1; off < 64; off <<= 1) {
        int x0 = __shfl_up(v0, off);
        int x1 = __shfl_up(v1, off);
        if (lane >= off) { v0 += x0; v1 += x1; }
    }
    int tot0 = __shfl(v0, 63);
    if (lane < nb) p[lane] = v0 - o0;                 // exclusive
    if (64 + lane < nb) p[64 + lane] = tot0 + v1 - o1;
}

__global__ __launch_bounds__(256) void write_rowptr_all(
        const int* __restrict__ cC, const int* __restrict__ cU, const int* __restrict__ cA,
        const int* __restrict__ pC, const int* __restrict__ pU, const int* __restrict__ pA,
        int* __restrict__ rpC, int* __restrict__ rpU, int* __restrict__ rpA,
        int* __restrict__ nxC, int* __restrict__ nxU, int* __restrict__ nxA,
        int nF, int nA, int nbF, int E)
{
    __shared__ int sc[256];
    int b = blockIdx.x, t = threadIdx.x;
    const int* cnt; const int* part; int* rp; int* nx; int n, lb;
    if (b < nbF)            { cnt = cC; part = pC; rp = rpC; nx = nxC; n = nF; lb = b; }
    else if (b < 2 * nbF)   { cnt = cU; part = pU; rp = rpU; nx = nxU; n = nF; lb = b - nbF; }
    else                    { cnt = cA; part = pA; rp = rpA; nx = nxA; n = nA; lb = b - 2 * nbF; }
    int base = lb * SCAN_CHUNK;
    int loc[8]; int s = 0;
    #pragma unroll
    for (int i = 0; i < 8; ++i) {
        int idx = base + t * 8 + i;
        int v = (idx < n) ? cnt[idx] : 0;
        loc[i] = s; s += v;
    }
    sc[t] = s; __syncthreads();
    for (int st = 1; st < 256; st <<= 1) {
        int v = (t >= st) ? sc[t - st] : 0;
        __syncthreads();
        sc[t] += v;
        __syncthreads();
    }
    int off = part[lb] + (t > 0 ? sc[t - 1] : 0);
    #pragma unroll
    for (int i = 0; i < 8; ++i) {
        int idx = base + t * 8 + i;
        if (idx < n) { int v = off + loc[i]; rp[idx] = v; nx[idx] = v; }
    }
    if (lb == 0 && t == 0) rp[n] = E;
}

// ---- proj body (shared) ----
template<int K>
__device__ __forceinline__ void proj_body(const float* __restrict__ x,
        const float* __restrict__ wt, const float* __restrict__ bias,
        float* __restrict__ hout, int i0, int nN, float4* smem)
{
    constexpr int KQ = K / 4;
    const int t = threadIdx.x;
    for (int idx = t; idx < 64 * KQ; idx += 256) {
        int n = idx / KQ, k4 = idx - n * KQ;
        float4 v = make_float4(0.f, 0.f, 0.f, 0.f);
        if (i0 + n < nN)
            v = *reinterpret_cast<const float4*>(x + (size_t)(i0 + n) * K + k4 * 4);
        smem[n * KQ + (k4 ^ ((n >> 2) & 7))] = v;
    }
    __syncthreads();
    const int og = t & 15, ng = t >> 4;
    float4 acc[4];
    #pragma unroll
    for (int j = 0; j < 4; ++j) acc[j] = make_float4(0.f, 0.f, 0.f, 0.f);
    const float4* w4 = reinterpret_cast<const float4*>(wt);
    for (int k4 = 0; k4 < KQ; ++k4) {
        float4 w0 = w4[(4 * k4 + 0) * 16 + og];
        float4 w1 = w4[(4 * k4 + 1) * 16 + og];
        float4 w2 = w4[(4 * k4 + 2) * 16 + og];
        float4 w3 = w4[(4 * k4 + 3) * 16 + og];
        #pragma unroll
        for (int j = 0; j < 4; ++j) {
            int n = ng * 4 + j;
            float4 xv = smem[n * KQ + (k4 ^ ((n >> 2) & 7))];
            fma4(acc[j], xv.x, w0); fma4(acc[j], xv.y, w1);
            fma4(acc[j], xv.z, w2); fma4(acc[j], xv.w, w3);
        }
    }
    float4 b = reinterpret_cast<const float4*>(bias)[og];
    #pragma unroll
    for (int j = 0; j < 4; ++j) {
        int node = i0 + ng * 4 + j;
        if (node < nN) {
            float4 o;
            o.x = fmaxf(acc[j].x + b.x, 0.f);
            o.y = fmaxf(acc[j].y + b.y, 0.f);
            o.z = fmaxf(acc[j].z + b.z, 0.f);
            o.w = fmaxf(acc[j].w + b.w, 0.f);
            *reinterpret_cast<float4*>(hout + (size_t)node * H + og * 4) = o;
        }
    }
}

// ---- K5: CSR fill + both projections in one launch ----
__global__ __launch_bounds__(256) void fill_and_proj(
        const int* __restrict__ sC, const int* __restrict__ dC,
        const int* __restrict__ sU, const int* __restrict__ dU,
        const int* __restrict__ sA, const int* __restrict__ dA,
        int* __restrict__ nxC, int* __restrict__ nxU, int* __restrict__ nxA,
        int* __restrict__ colC, int* __restrict__ colU, int* __restrict__ colA, int E,
        int fillB,
        const float* __restrict__ xf, const float* __restrict__ wtf,
        const float* __restrict__ bf, float* __restrict__ hf,
        const float* __restrict__ xa, const float* __restrict__ wta,
        const float* __restrict__ ba, float* __restrict__ ha)
{
    __shared__ float4 smem[64 * 32];
    int b = blockIdx.x;
    if (b < fillB) {
        int i = b * 256 + threadIdx.x;
        if (i >= 3 * E) return;
        int rel = i / E, e = i - rel * E;
        if (rel == 0)      { int pos = atomicAdd(&nxC[dC[e]], 1); colC[pos] = sC[e]; }
        else if (rel == 1) { int pos = atomicAdd(&nxU[dU[e]], 1); colU[pos] = sU[e]; }
        else               { int pos = atomicAdd(&nxA[dA[e]], 1); colA[pos] = sA[e]; }
    } else {
        int b2 = b - fillB;
        if (b2 < NBF) proj_body<128>(xf, wtf, bf, hf, b2 * 64, N_FUNC, smem);
        else          proj_body<64>(xa, wta, ba, ha, (b2 - NBF) * 64, N_API, smem);
    }
}

// ---- shared GEMM-accumulate: acc[j] += X(row ng*4+j, swizzled LDS) @ wt ----
__device__ __forceinline__ void gemm_acc(const float4* X, const float4* __restrict__ wt4,
        int og, int ng, float4 acc[4])
{
    for (int k4 = 0; k4 < 16; ++k4) {
        float4 w0 = wt4[(4 * k4 + 0) * 16 + og];
        float4 w1 = wt4[(4 * k4 + 1) * 16 + og];
        float4 w2 = wt4[(4 * k4 + 2) * 16 + og];
        float4 w3 = wt4[(4 * k4 + 3) * 16 + og];
        #pragma unroll
        for (int j = 0; j < 4; ++j) {
            int n = ng * 4 + j;
            float4 xv = X[n * 16 + (k4 ^ ((n >> 2) & 7))];
            fma4(acc[j], xv.x, w0); fma4(acc[j], xv.y, w1);
            fma4(acc[j], xv.z, w2); fma4(acc[j], xv.w, w3);
        }
    }
}

// 4-way interleaved CSR gather into a[4] (rows p*16+g, dims 4L..4L+3)
__device__ __forceinline__ void gather4(const float* __restrict__ src,
        const int* __restrict__ col, int j[4], const int e[4], int L, float4 a[4])
{
    while (j[0] < e[0] || j[1] < e[1] || j[2] < e[2] || j[3] < e[3]) {
        float4 v[4]; bool act[4];
        #pragma unroll
        for (int p = 0; p < 4; ++p) {
            act[p] = j[p] < e[p];
            if (act[p]) {
                int s = col[j[p]++];
                v[p] = *reinterpret_cast<const float4*>(src + (size_t)s * H + L * 4);
            }
        }
        #pragma unroll
        for (int p = 0; p < 4; ++p) if (act[p]) add4(a[p], v[p]);
    }
}

// ---- fused layer: one 16KB LDS buffer, sequential gather->GEMM phases ----
__global__ __launch_bounds__(256, 6) void layer_both(
        const float* __restrict__ hf_old, const float* __restrict__ ha_old,
        float* __restrict__ hf_new, float* __restrict__ ha_new,
        const int* __restrict__ rpC, const int* __restrict__ colC,
        const int* __restrict__ rpU, const int* __restrict__ colU,
        const int* __restrict__ rpA, const int* __restrict__ colA,
        const float* __restrict__ wtr, const float* __restrict__ wtlc,
        const float* __restrict__ wtlu,
        const float* __restrict__ wtruse, const float* __restrict__ wtluse,
        const float* __restrict__ bias_c, const float* __restrict__ bias_u,
        const float* __restrict__ bias_a)
{
    __shared__ float4 X[64 * 16];    // 16 KB, reused across phases
    const int b = blockIdx.x;
    const int t = threadIdx.x;
    const int L = t & 15, g = t >> 4;      // gather role: rows p*16+g, dims 4L..
    const int og = t & 15, ng = t >> 4;    // gemm role

    float4 acc[4];
    #pragma unroll
    for (int j = 0; j < 4; ++j) acc[j] = make_float4(0.f, 0.f, 0.f, 0.f);

    if (b < NBF) {
        const int i0 = b * 64;
        // ---- Phase 1: mean over calls (hf_old) -> GEMM Wlc ----
        {
            int j[4], e[4]; float4 a[4];
            #pragma unroll
            for (int p = 0; p < 4; ++p) {
                int node = i0 + p * 16 + g;
                j[p] = rpC[node]; e[p] = rpC[node + 1];
                a[p] = make_float4(0.f, 0.f, 0.f, 0.f);
            }
            int d[4];
            #pragma unroll
            for (int p = 0; p < 4; ++p) d[p] = e[p] - j[p];
            gather4(hf_old, colC, j, e, L, a);
            #pragma unroll
            for (int p = 0; p < 4; ++p) {
                int n = p * 16 + g;
                scl4(a[p], 1.0f / (float)max(d[p], 1));
                X[n * 16 + (L ^ ((n >> 2) & 7))] = a[p];
            }
        }
        __syncthreads();
        gemm_acc(X, reinterpret_cast<const float4*>(wtlc), og, ng, acc);
        __syncthreads();
        // ---- Phase 2: mean over usedby (ha_old) -> GEMM Wlu ----
        {
            int j[4], e[4]; float4 a[4];
            #pragma unroll
            for (int p = 0; p < 4; ++p) {
                int node = i0 + p * 16 + g;
                j[p] = rpU[node]; e[p] = rpU[node + 1];
                a[p] = make_float4(0.f, 0.f, 0.f, 0.f);
            }
            int d[4];
            #pragma unroll
            for (int p = 0; p < 4; ++p) d[p] = e[p] - j[p];
            gather4(ha_old, colU, j, e, L, a);
            #pragma unroll
            for (int p = 0; p < 4; ++p) {
                int n = p * 16 + g;
                scl4(a[p], 1.0f / (float)max(d[p], 1));
                X[n * 16 + (L ^ ((n >> 2) & 7))] = a[p];
            }
        }
        __syncthreads();
        gemm_acc(X, reinterpret_cast<const float4*>(wtlu), og, ng, acc);
        __syncthreads();
        // ---- Phase 3: own rows (coalesced) -> GEMM Wr ----
        for (int idx = t; idx < 1024; idx += 256) {
            int n = idx >> 4, k4 = idx & 15;
            X[n * 16 + (k4 ^ ((n >> 2) & 7))] =
                *reinterpret_cast<const float4*>(hf_old + (size_t)(i0 + n) * H + k4 * 4);
        }
        __syncthreads();
        gemm_acc(X, reinterpret_cast<const float4*>(wtr), og, ng, acc);
        // ---- epilogue ----
        float4 ba = reinterpret_cast<const float4*>(bias_c)[og];
        float4 bb = reinterpret_cast<const float4*>(bias_u)[og];
        float4 bv = make_float4(ba.x + bb.x, ba.y + bb.y, ba.z + bb.z, ba.w + bb.w);
        #pragma unroll
        for (int j = 0; j < 4; ++j) {
            int node = i0 + ng * 4 + j;
            float4 o;
            o.x = fmaxf(acc[j].x + bv.x, 0.f);
            o.y = fmaxf(acc[j].y + bv.y, 0.f);
            o.z = fmaxf(acc[j].z + bv.z, 0.f);
            o.w = fmaxf(acc[j].w + bv.w, 0.f);
            *reinterpret_cast<float4*>(hf_new + (size_t)node * H + og * 4) = o;
        }
    } else {
        const int i0 = (b - NBF) * 64;
        // ---- Phase 1: mean over uses (hf_old) -> GEMM Wluse ----
        {
            int j[4], e[4]; float4 a[4];
            #pragma unroll
            for (int p = 0; p < 4; ++p) {
                int node = i0 + p * 16 + g;
                if (node < N_API) { j[p] = rpA[node]; e[p] = rpA[node + 1]; }
                else { j[p] = 0; e[p] = 0; }
                a[p] = make_float4(0.f, 0.f, 0.f, 0.f);
            }
            int d[4];
            #pragma unroll
            for (int p = 0; p < 4; ++p) d[p] = e[p] - j[p];
            gather4(hf_old, colA, j, e, L, a);
            #pragma unroll
            for (int p = 0; p < 4; ++p) {
                int n = p * 16 + g;
                scl4(a[p], 1.0f / (float)max(d[p], 1));
                X[n * 16 + (L ^ ((n >> 2) & 7))] = a[p];
            }
        }
        __syncthreads();
        gemm_acc(X, reinterpret_cast<const float4*>(wtluse), og, ng, acc);
        __syncthreads();
        // ---- Phase 2: own rows -> GEMM Wruse ----
        for (int idx = t; idx < 1024; idx += 256) {
            int n = idx >> 4, k4 = idx & 15;
            int node = i0 + n;
            float4 v = make_float4(0.f, 0.f, 0.f, 0.f);
            if (node < N_API)
                v = *reinterpret_cast<const float4*>(ha_old + (size_t)node * H + k4 * 4);
            X[n * 16 + (k4 ^ ((n >> 2) & 7))] = v;
        }
        __syncthreads();
        gemm_acc(X, reinterpret_cast<const float4*>(wtruse), og, ng, acc);
        float4 bv = reinterpret_cast<const float4*>(bias_a)[og];
        #pragma unroll
        for (int j = 0; j < 4; ++j) {
            int node = i0 + ng * 4 + j;
            if (node < N_API) {
                float4 o;
                o.x = fmaxf(acc[j].x + bv.x, 0.f);
                o.y = fmaxf(acc[j].y + bv.y, 0.f);
                o.z = fmaxf(acc[j].z + bv.z, 0.f);
                o.w = fmaxf(acc[j].w + bv.w, 0.f);
                *reinterpret_cast<float4*>(ha_new + (size_t)node * H + og * 4) = o;
            }
        }
    }
}

__global__ __launch_bounds__(256) void pool_both(const float* __restrict__ hf,
        const float* __restrict__ ha, float* __restrict__ pooled)
{
    __shared__ float red[4][64];
    const float* h; float* out; int nN, bid, nb;
    if (blockIdx.x < 512) { h = hf; out = pooled;      nN = N_FUNC; bid = blockIdx.x;       nb = 512; }
    else                  { h = ha; out = pooled + 64; nN = N_API;  bid = blockIdx.x - 512; nb = 128; }
    int c = threadIdx.x & 63, rl = threadIdx.x >> 6;
    float s = 0.f;
    for (int r = bid * 4 + rl; r < nN; r += nb * 4)
        s += h[(size_t)r * H + c];
    red[rl][c] = s;
    __syncthreads();
    if (threadIdx.x < 64)
        atomicAdd(&out[c], red[0][c] + red[1][c] + red[2][c] + red[3][c]);
}

__global__ __launch_bounds__(128) void classifier_kernel(const float* __restrict__ pooled,
        const float* __restrict__ Wc1, const float* __restrict__ bc1,
        const float* __restrict__ Wc2, const float* __restrict__ bc2,
        float* __restrict__ out)
{
    __shared__ float ps[128];
    __shared__ float z1[64];
    int t = threadIdx.x;
    ps[t] = pooled[t] * (t < 64 ? (1.0f / N_FUNC) : (1.0f / N_API));
    __syncthreads();
    if (t < 64) {
        float a = bc1[t];
        for (int k = 0; k < 128; ++k) a = fmaf(ps[k], Wc1[t * 128 + k], a);
        z1[t] = fmaxf(a, 0.f);
    }
    __syncthreads();
    if (t < 2) {
        float a = bc2[t];
        for (int j = 0; j < 64; ++j) a = fmaf(z1[j], Wc2[t * 64 + j], a);
        out[t] = a;
    }
}

extern "C" void kernel_launch(void* const* d_in, const int* in_sizes, int n_in,
                              void* d_out, int out_size, void* d_ws, size_t ws_size,
                              hipStream_t stream)
{
    const float* x_func    = (const float*)d_in[0];
    const float* x_api     = (const float*)d_in[1];
    const float* w_in_func = (const float*)d_in[2];
    const float* b_in_func = (const float*)d_in[3];
    const float* w_in_api  = (const float*)d_in[4];
    const float* b_in_api  = (const float*)d_in[5];
    const float* Wl_calls  = (const float*)d_in[6];
    const float* bl_calls  = (const float*)d_in[7];
    const float* Wr_calls  = (const float*)d_in[8];
    const float* Wl_uses   = (const float*)d_in[9];
    const float* bl_uses   = (const float*)d_in[10];
    const float* Wr_uses   = (const float*)d_in[11];
    const float* Wl_usedby = (const float*)d_in[12];
    const float* bl_usedby = (const float*)d_in[13];
    const float* Wr_usedby = (const float*)d_in[14];
    const float* Wc1       = (const float*)d_in[15];
    const float* bc1       = (const float*)d_in[16];
    const float* Wc2       = (const float*)d_in[17];
    const float* bc2       = (const float*)d_in[18];
    const int*   ei_calls  = (const int*)d_in[19];
    const int*   ei_uses   = (const int*)d_in[20];
    const int*   ei_usedby = (const int*)d_in[21];
    const int E = in_sizes[19] / 2;

    float* ws = (float*)d_ws;
    size_t off = 0;
    float* hf0 = ws + off; off += (size_t)N_FUNC * H;
    float* hf1 = ws + off; off += (size_t)N_FUNC * H;
    float* ha0 = ws + off; off += (size_t)N_API * H;
    float* ha1 = ws + off; off += (size_t)N_API * H;
    float* prep = ws + off; off += 12288 + 10 * 4096;
    int* cntC = (int*)(ws + off); off += N_FUNC;   // cnt block + pooled contiguous for 1 memset
    int* cntU = (int*)(ws + off); off += N_FUNC;
    int* cntA = (int*)(ws + off); off += N_API;
    float* pooled = ws + off; off += 128;
    int* rpC = (int*)(ws + off); off += N_FUNC + 1;
    int* rpU = (int*)(ws + off); off += N_FUNC + 1;
    int* rpA = (int*)(ws + off); off += N_API + 1;
    int* nxC = (int*)(ws + off); off += N_FUNC + 1;
    int* nxU = (int*)(ws + off); off += N_FUNC + 1;
    int* nxA = (int*)(ws + off); off += N_API + 1;
    int* colC = (int*)(ws + off); off += E;
    int* colU = (int*)(ws + off); off += E;
    int* colA = (int*)(ws + off); off += E;
    int* partC = (int*)(ws + off); off += 128;
    int* partU = (int*)(ws + off); off += 128;
    int* partA = (int*)(ws + off); off += 128;

    const int nbF = (N_FUNC + SCAN_CHUNK - 1) / SCAN_CHUNK;  // 98
    const int nbA = (N_API + SCAN_CHUNK - 1) / SCAN_CHUNK;   // 25
    const int fillB = (3 * E + 255) / 256;

    hipMemsetAsync(cntC, 0, (size_t)(2 * N_FUNC + N_API + 128) * sizeof(float), stream);

    prep_and_count<<<PREP_BLOCKS + fillB, 256, 0, stream>>>(
            w_in_func, w_in_api, Wl_calls, Wr_calls, Wl_uses, Wr_uses,
            Wl_usedby, Wr_usedby, prep,
            ei_calls + E, ei_usedby + E, ei_uses + E, cntC, cntU, cntA, E);

    float* wt_in_func = prep;
    float* wt_in_api  = prep + 8192;
    float* wt_r[NLAYERS], *wt_lc[NLAYERS], *wt_lu[NLAYERS], *wt_luse[NLAYERS], *wt_ruse[NLAYERS];
    for (int l = 0; l < NLAYERS; ++l) {
        wt_r[l]    = prep + 12288 + (l * 5 + 0) * 4096;
        wt_lc[l]   = prep + 12288 + (l * 5 + 1) * 4096;
        wt_lu[l]   = prep + 12288 + (l * 5 + 2) * 4096;
        wt_luse[l] = prep + 12288 + (l * 5 + 3) * 4096;
        wt_ruse[l] = prep + 12288 + (l * 5 + 4) * 4096;
    }

    block_sums_all<<<2 * nbF + nbA, 256, 0, stream>>>(
            cntC, cntU, cntA, partC, partU, partA, N_FUNC, N_API, nbF);
    scan_small_all<<<1, 192, 0, stream>>>(partC, partU, partA, nbF, nbA);
    write_rowptr_all<<<2 * nbF + nbA, 256, 0, stream>>>(
            cntC, cntU, cntA, partC, partU, partA,
            rpC, rpU, rpA, nxC, nxU, nxA, N_FUNC, N_API, nbF, E);
    fill_and_proj<<<fillB + NBF + NBA, 256, 0, stream>>>(
            ei_calls, ei_calls + E, ei_usedby, ei_usedby + E, ei_uses, ei_uses + E,
            nxC, nxU, nxA, colC, colU, colA, E, fillB,
            x_func, wt_in_func, b_in_func, hf0,
            x_api, wt_in_api, b_in_api, ha0);

    float* hf[2] = { hf0, hf1 };
    float* ha[2] = { ha0, ha1 };
    for (int l = 0; l < NLAYERS; ++l) {
        int cur = l & 1, nxt = cur ^ 1;
        layer_both<<<NBF + NBA, 256, 0, stream>>>(
                hf[cur], ha[cur], hf[nxt], ha[nxt],
                rpC, colC, rpU, colU, rpA, colA,
                wt_r[l], wt_lc[l], wt_lu[l], wt_ruse[l], wt_luse[l],
                bl_calls + l * 64, bl_usedby + l * 64, bl_uses + l * 64);
    }

    pool_both<<<640, 256, 0, stream>>>(hf[0], ha[0], pooled);
    classifier_kernel<<<1, 128, 0, stream>>>(pooled, Wc1, bc1, Wc2, bc2, (float*)d_out);
}